// Round 1
// baseline (273.226 us; speedup 1.0000x reference)
//
#include <hip/hip_runtime.h>
#include <hip/hip_bf16.h>

// Problem constants (B=4, N=2048, C=768, H=12, D=64)
#define BB 4
#define NN 2048
#define CC 768
#define HH 12
#define DD 64

typedef __bf16 bf16;
typedef __attribute__((ext_vector_type(8))) __bf16 bf16x8;
typedef __attribute__((ext_vector_type(4))) __bf16 bf16x4;
typedef __attribute__((ext_vector_type(4))) float f32x4;

// ---- workspace layout (bf16 elems) ----------------------------------------
#define SZ_X    (BB * NN * CC)              // 6291456
#define SZ_QKVW (3 * CC * CC)               // 1769472
#define SZ_PW   (CC * CC)                   // 589824
#define SZ_QKV  ((size_t)BB * NN * 3 * CC)  // 18874368

#define OFF_X    0
#define OFF_VT   0                          // aliases xb (x dead after QKV GEMM)
#define OFF_QW   (OFF_X + SZ_X)
#define OFF_PW   (OFF_QW + SZ_QKVW)
#define OFF_QKV  (OFF_PW + SZ_PW)           // end = 27525120 elems = 55.1 MB

// Direct-to-LDS 16B DMA; source chunk XOR-swizzled to kill read conflicts.
__device__ __forceinline__ void async16(const bf16* g, bf16* l) {
    __builtin_amdgcn_global_load_lds(
        (const __attribute__((address_space(1))) unsigned int*)g,
        (__attribute__((address_space(3))) unsigned int*)l, 16, 0, 0);
}

// ---------------------------------------------------------------------------
__global__ __launch_bounds__(256) void convert3(
    const float* __restrict__ x, const float* __restrict__ qkvw,
    const float* __restrict__ pw, bf16* __restrict__ ws) {
    const int t = blockIdx.x * 256 + threadIdx.x;
    const int S = gridDim.x * 256;
    for (int i = t; i < SZ_X;    i += S) ws[OFF_X + i]  = (bf16)x[i];
    for (int i = t; i < SZ_QKVW; i += S) ws[OFF_QW + i] = (bf16)qkvw[i];
    for (int i = t; i < SZ_PW;   i += S) ws[OFF_PW + i] = (bf16)pw[i];
}

// ---------------------------------------------------------------------------
// m97-style GEMM: 128x128 tile, BK=64, DMA staging, swizzled LDS (unchanged).
// ---------------------------------------------------------------------------
template <bool HAS_BIAS, typename OutT>
__global__ __launch_bounds__(256) void gemm128(
    const bf16* __restrict__ A, int lda, const bf16* __restrict__ W,
    const float* __restrict__ bias, OutT* __restrict__ C,
    int M, int Nn, int K) {
    __shared__ __align__(16) bf16 As[128 * 64];
    __shared__ __align__(16) bf16 Bs[128 * 64];
    const int tid  = threadIdx.x;
    const int wave = tid >> 6;
    const int lane = tid & 63;
    const int quad = lane >> 4;
    const int l16  = lane & 15;
    const int m0 = blockIdx.y * 128;
    const int n0 = blockIdx.x * 128;
    const int wm = (wave >> 1) * 64;
    const int wn = (wave & 1) * 64;
    const int srow = lane >> 3;
    const int swz  = (lane & 7) ^ srow;

    f32x4 acc[4][4];
#pragma unroll
    for (int i = 0; i < 4; ++i)
#pragma unroll
        for (int j = 0; j < 4; ++j) acc[i][j] = (f32x4){0.f, 0.f, 0.f, 0.f};

    for (int k0 = 0; k0 < K; k0 += 64) {
#pragma unroll
        for (int i = 0; i < 4; ++i) {
            int row = i * 32 + wave * 8 + srow;
            async16(A + (size_t)(m0 + row) * lda + k0 + swz * 8,
                    &As[(i * 32 + wave * 8) * 64]);
            async16(W + (size_t)(n0 + row) * K + k0 + swz * 8,
                    &Bs[(i * 32 + wave * 8) * 64]);
        }
        __syncthreads();
#pragma unroll
        for (int kk = 0; kk < 2; ++kk) {
            const int slot = ((kk * 4 + quad) ^ (l16 & 7)) * 8;
            bf16x8 af[4], bf[4];
#pragma unroll
            for (int mt = 0; mt < 4; ++mt)
                af[mt] = *(const bf16x8*)(&As[(wm + mt * 16 + l16) * 64 + slot]);
#pragma unroll
            for (int nt = 0; nt < 4; ++nt)
                bf[nt] = *(const bf16x8*)(&Bs[(wn + nt * 16 + l16) * 64 + slot]);
#pragma unroll
            for (int mt = 0; mt < 4; ++mt)
#pragma unroll
                for (int nt = 0; nt < 4; ++nt)
                    acc[mt][nt] = __builtin_amdgcn_mfma_f32_16x16x32_bf16(
                        af[mt], bf[nt], acc[mt][nt], 0, 0, 0);
        }
        __syncthreads();
    }
#pragma unroll
    for (int mt = 0; mt < 4; ++mt)
#pragma unroll
        for (int nt = 0; nt < 4; ++nt)
#pragma unroll
            for (int r = 0; r < 4; ++r) {
                int row = m0 + wm + mt * 16 + quad * 4 + r;
                int col = n0 + wn + nt * 16 + l16;
                float v = acc[mt][nt][r];
                if (HAS_BIAS) v += bias[col];
                C[(size_t)row * Nn + col] = (OutT)v;
            }
}

// ---------------------------------------------------------------------------
// Transpose v-slice of qkv [B*N][3C] -> Vt [B*H][D][N]  (unchanged, verified)
// ---------------------------------------------------------------------------
__global__ __launch_bounds__(256) void transpose_v(
    const bf16* __restrict__ qkv, bf16* __restrict__ Vt) {
    __shared__ __align__(16) bf16 Ts[64 * 64];
    const int t = threadIdx.x;
    const int bh = blockIdx.x;
    const int kt = blockIdx.y;
    const int b = bh / HH, h = bh % HH;
    const size_t rs = 3 * CC;
    const bf16* src = qkv + (size_t)b * NN * rs + 2 * CC + h * DD;
    {
        const int keyl = t >> 2;
        const int d0   = (t & 3) * 16;
#pragma unroll
        for (int half = 0; half < 2; ++half) {
            int dd = d0 + half * 8;
            bf16x8 v = *(const bf16x8*)(src + (size_t)(kt * 64 + keyl) * rs + dd);
            int dc = dd >> 3;
            *(bf16x8*)(&Ts[keyl * 64 + ((dc ^ (keyl >> 3)) * 8)]) = v;
        }
    }
    __syncthreads();
#pragma unroll
    for (int p = 0; p < 2; ++p) {
        const int d  = p * 32 + (t >> 3);
        const int kc = (t & 7) * 8;
        bf16x8 v;
#pragma unroll
        for (int j = 0; j < 8; ++j) {
            int key = kc + j;
            v[j] = Ts[key * 64 + (((d >> 3) ^ (key >> 3)) * 8 + (d & 7))];
        }
        *(bf16x8*)(Vt + ((size_t)bh * DD + d) * NN + kt * 64 + kc) = v;
    }
}

// ---------------------------------------------------------------------------
// RMSNorm + RoPE in-place on q,k.  q-rows are additionally scaled by
// CEXP = 0.125*log2(e) in fp32 before the single bf16 rounding, so QK^T
// scores exit the MFMA already in exp2-domain (flash does p = exp2(s), no
// per-element fma, no shift — softmax is shift-invariant and the constant
// cancels in accO/lsum; range |s'| <= 23.1 is safe in bf16/fp32).
// ---------------------------------------------------------------------------
__global__ __launch_bounds__(256) void norm_rope(
    bf16* __restrict__ qkv, const float* __restrict__ cosb,
    const float* __restrict__ sinb, const float* __restrict__ qw,
    const float* __restrict__ kw) {
    const int lane = threadIdx.x & 63;
    const int wave = threadIdx.x >> 6;
    const int job = blockIdx.x * 4 + wave;
    const int h = job % HH;
    const int s = (job / HH) & 1;
    const int bn = job / (2 * HH);
    const int n = bn % NN;

    bf16* row = qkv + (size_t)bn * (3 * CC) + s * CC + h * DD;
    float x = (float)row[lane];
    float ss = x * x;
#pragma unroll
    for (int m = 32; m >= 1; m >>= 1) ss += __shfl_xor(ss, m, 64);
    float r = rsqrtf(ss * (1.0f / 64.0f) + 1e-6f);
    x = x * r * ((s == 0) ? qw[lane] : kw[lane]);
    float xp = __shfl_xor(x, 32, 64);
    int j = lane & 31;
    float c  = cosb[n * 32 + j];
    float si = sinb[n * 32 + j];
    x = (lane < 32) ? (x * c - xp * si) : (x * c + xp * si);
    if (s == 0) x *= 0.18033688f;   // CEXP folded into q (fp32, pre-rounding)
    row[lane] = (bf16)x;
}

// ---------------------------------------------------------------------------
// Flash attention. NEW this round: double-buffered K/V staging (2-phase
// pipeline, T3-lite): issue next tile's global_load_lds DMAs BEFORE computing
// the current tile, so the single end-of-tile __syncthreads (whose implicit
// s_waitcnt vmcnt(0) drains them) has the whole tile's compute to cover the
// memory latency. Also collapses 2 barriers/tile -> 1 barrier/tile.
// LDS: 2*(8K Ks + 8K Vs) + 18K Ps = 50 KB -> still 3 blocks/CU (grid-capped).
// Rider: s_setprio(1) around MFMA clusters (T5, attn +4-7% evidence m191).
// ---------------------------------------------------------------------------
__global__ __launch_bounds__(256) void flash_attn(
    const bf16* __restrict__ qkv, const bf16* __restrict__ Vt,
    bf16* __restrict__ Oqkv) {
    __shared__ __align__(16) bf16 Ks[2][64 * 64];    // [buf][key][d] swizzled
    __shared__ __align__(16) bf16 Vs[2][64 * 64];    // [buf][d][key] swizzled
    __shared__ __align__(16) bf16 Ps[4][32 * 72];    // per-wave [q][key], padded
    const int tid  = threadIdx.x;
    const int wave = tid >> 6;
    const int lane = tid & 63;
    const int quad = lane >> 4;
    const int l16  = lane & 15;
    const int r7   = l16 & 7;
    const int bh = blockIdx.x;
    const int qt = blockIdx.y;
    const int b = bh / HH, h = bh % HH;
    const size_t rs = 3 * CC;
    const bf16* Qb  = qkv + (size_t)b * NN * rs + h * DD;
    const bf16* Kb  = Qb + CC;
    const bf16* Vtb = Vt + (size_t)bh * DD * NN;

    const int srow = lane >> 3;
    const int swz  = (lane & 7) ^ srow;

    bf16x8 qf[2][2];
#pragma unroll
    for (int f = 0; f < 2; ++f) {
        const int qrow = qt * 128 + wave * 32 + f * 16 + l16;
#pragma unroll
        for (int hf = 0; hf < 2; ++hf)
            qf[f][hf] = *(const bf16x8*)(Qb + (size_t)qrow * rs + hf * 32 + quad * 8);
    }

    f32x4 accO[2][4];
#pragma unroll
    for (int f = 0; f < 2; ++f)
#pragma unroll
        for (int i = 0; i < 4; ++i) accO[f][i] = (f32x4){0.f, 0.f, 0.f, 0.f};
    float lsum[2] = {0.f, 0.f};

    // prologue: stage tile 0 into buffer 0
#pragma unroll
    for (int i = 0; i < 2; ++i) {
        int row = i * 32 + wave * 8 + srow;
        async16(Kb + (size_t)row * rs + swz * 8,
                &Ks[0][(i * 32 + wave * 8) * 64]);
        async16(Vtb + (size_t)row * NN + swz * 8,
                &Vs[0][(i * 32 + wave * 8) * 64]);
    }
    __syncthreads();   // implicit vmcnt(0): tile 0 resident

    int cur = 0;
    for (int kt = 0; kt < NN / 64; ++kt) {
        // issue NEXT tile's DMAs into the other buffer before computing
        if (kt < NN / 64 - 1) {
#pragma unroll
            for (int i = 0; i < 2; ++i) {
                int row = i * 32 + wave * 8 + srow;
                async16(Kb + (size_t)((kt + 1) * 64 + row) * rs + swz * 8,
                        &Ks[cur ^ 1][(i * 32 + wave * 8) * 64]);
                async16(Vtb + (size_t)row * NN + (kt + 1) * 64 + swz * 8,
                        &Vs[cur ^ 1][(i * 32 + wave * 8) * 64]);
            }
        }
        const bf16* Kc = Ks[cur];
        const bf16* Vc = Vs[cur];

        // S^T = (Q K^T)^T via swapped operands; scores already exp2-domain
        f32x4 s[2][4];
        __builtin_amdgcn_s_setprio(1);
#pragma unroll
        for (int nt = 0; nt < 4; ++nt) {
            const int row = nt * 16 + l16;
            bf16x8 kf0 = *(const bf16x8*)(&Kc[row * 64 + (quad ^ r7) * 8]);
            bf16x8 kf1 = *(const bf16x8*)(&Kc[row * 64 + ((quad + 4) ^ r7) * 8]);
#pragma unroll
            for (int f = 0; f < 2; ++f) {
                f32x4 z = (f32x4){0.f, 0.f, 0.f, 0.f};
                z = __builtin_amdgcn_mfma_f32_16x16x32_bf16(kf0, qf[f][0], z, 0, 0, 0);
                s[f][nt] = __builtin_amdgcn_mfma_f32_16x16x32_bf16(kf1, qf[f][1], z, 0, 0, 0);
            }
        }
        __builtin_amdgcn_s_setprio(0);

        // p = exp2(s); packed b64 stores (4 consecutive keys per store)
#pragma unroll
        for (int f = 0; f < 2; ++f)
#pragma unroll
            for (int nt = 0; nt < 4; ++nt) {
                bf16x4 pk;
#pragma unroll
                for (int r = 0; r < 4; ++r) {
                    float pv = __builtin_amdgcn_exp2f(s[f][nt][r]);
                    lsum[f] += pv;
                    pk[r] = (bf16)pv;
                }
                *(bf16x4*)(&Ps[wave][(f * 16 + l16) * 72 + nt * 16 + quad * 4]) = pk;
            }
        // Ps wave-private: wave-local DS drain + compiler fence
        __asm__ volatile("s_waitcnt lgkmcnt(0)" ::: "memory");

        bf16x8 pf0[2], pf1[2];
#pragma unroll
        for (int f = 0; f < 2; ++f) {
            pf0[f] = *(const bf16x8*)(&Ps[wave][(f * 16 + l16) * 72 + quad * 8]);
            pf1[f] = *(const bf16x8*)(&Ps[wave][(f * 16 + l16) * 72 + 32 + quad * 8]);
        }
        __builtin_amdgcn_s_setprio(1);
#pragma unroll
        for (int nt = 0; nt < 4; ++nt) {
            const int rowd = nt * 16 + l16;
            bf16x8 vf0 = *(const bf16x8*)(&Vc[rowd * 64 + (quad ^ r7) * 8]);
            bf16x8 vf1 = *(const bf16x8*)(&Vc[rowd * 64 + ((quad + 4) ^ r7) * 8]);
#pragma unroll
            for (int f = 0; f < 2; ++f) {
                accO[f][nt] = __builtin_amdgcn_mfma_f32_16x16x32_bf16(pf0[f], vf0, accO[f][nt], 0, 0, 0);
                accO[f][nt] = __builtin_amdgcn_mfma_f32_16x16x32_bf16(pf1[f], vf1, accO[f][nt], 0, 0, 0);
            }
        }
        __builtin_amdgcn_s_setprio(0);

        // single barrier per tile: implicit vmcnt(0) covers the prefetch,
        // and guarantees everyone is done reading buf[cur] before it is
        // overwritten next iteration.
        __syncthreads();
        cur ^= 1;
    }

    // lsum: reduce over the 4 quads sharing l16 (lane's q = f*16+l16)
#pragma unroll
    for (int f = 0; f < 2; ++f) {
        lsum[f] += __shfl_xor(lsum[f], 16, 64);
        lsum[f] += __shfl_xor(lsum[f], 32, 64);
    }

    // epilogue: accO row q = f*16+quad*4+r; fetch 1/lsum from lane quad*4+r
#pragma unroll
    for (int f = 0; f < 2; ++f)
#pragma unroll
        for (int r = 0; r < 4; ++r) {
            float inv = 1.0f / __shfl(lsum[f], quad * 4 + r, 64);
            int n = qt * 128 + wave * 32 + f * 16 + quad * 4 + r;
#pragma unroll
            for (int nt = 0; nt < 4; ++nt) {
                int col = h * DD + nt * 16 + l16;
                Oqkv[(size_t)(b * NN + n) * rs + 2 * CC + col] = (bf16)(accO[f][nt][r] * inv);
            }
        }
}

// ---------------------------------------------------------------------------
extern "C" void kernel_launch(void* const* d_in, const int* in_sizes, int n_in,
                              void* d_out, int out_size, void* d_ws, size_t ws_size,
                              hipStream_t stream) {
    const float* x     = (const float*)d_in[0];
    const float* cosb  = (const float*)d_in[1];
    const float* sinb  = (const float*)d_in[2];
    const float* qkv_w = (const float*)d_in[3];
    const float* qnw   = (const float*)d_in[4];
    const float* knw   = (const float*)d_in[5];
    const float* pw    = (const float*)d_in[6];
    const float* pb    = (const float*)d_in[7];
    float* out = (float*)d_out;

    bf16* ws  = (bf16*)d_ws;
    bf16* xb  = ws + OFF_X;
    bf16* vt  = ws + OFF_VT;   // reuses xb after QKV GEMM
    bf16* qwb = ws + OFF_QW;
    bf16* pwb = ws + OFF_PW;
    bf16* qkv = ws + OFF_QKV;

    const int M = BB * NN;  // 8192

    // 0) cast MFMA operands to bf16
    convert3<<<1024, 256, 0, stream>>>(x, qkv_w, pw, ws);

    // 1) QKV projection -> qkv [B*N][3C] (bf16); 128x128 tiles
    dim3 g1(3 * CC / 128, M / 128);
    gemm128<false, bf16><<<g1, 256, 0, stream>>>(xb, CC, qwb, nullptr, qkv, M, 3 * CC, CC);

    // 2) transpose v-slice -> Vt [B*H][D][N]
    dim3 g2(BB * HH, NN / 64);
    transpose_v<<<g2, 256, 0, stream>>>(qkv, vt);

    // 3) RMSNorm + RoPE in place on q,k (q pre-scaled by CEXP)
    norm_rope<<<(BB * NN * 2 * HH) / 4, 256, 0, stream>>>(qkv, cosb, sinb, qnw, knw);

    // 4) Flash attention -> v-slice of qkv; 128 q-rows, 64-key tiles
    dim3 g4(BB * HH, NN / 128);
    flash_attn<<<g4, 256, 0, stream>>>(qkv, vt, qkv);

    // 5) Output projection (+fp32 bias) -> d_out; A = v-slice, lda = 3C
    dim3 g5(CC / 128, M / 128);
    gemm128<true, float><<<g5, 256, 0, stream>>>(qkv + 2 * CC, 3 * CC, pwb, pb, out, M, CC, CC);
}

// Round 2
// 266.024 us; speedup vs baseline: 1.0271x; 1.0271x over previous
//
#include <hip/hip_runtime.h>
#include <hip/hip_bf16.h>

// Problem constants (B=4, N=2048, C=768, H=12, D=64)
#define BB 4
#define NN 2048
#define CC 768
#define HH 12
#define DD 64

typedef __bf16 bf16;
typedef __attribute__((ext_vector_type(8))) __bf16 bf16x8;
typedef __attribute__((ext_vector_type(4))) __bf16 bf16x4;
typedef __attribute__((ext_vector_type(4))) float f32x4;
typedef __attribute__((ext_vector_type(4))) int i32x4;

// ---- workspace layout (bf16 elems) ----------------------------------------
#define SZ_X    (BB * NN * CC)              // 6291456
#define SZ_QKVW (3 * CC * CC)               // 1769472
#define SZ_PW   (CC * CC)                   // 589824
#define SZ_QKV  ((size_t)BB * NN * 3 * CC)  // 18874368

#define OFF_X    0
#define OFF_VT   0                          // aliases xb (x dead after QKV GEMM)
#define OFF_QW   (OFF_X + SZ_X)
#define OFF_PW   (OFF_QW + SZ_QKVW)
#define OFF_QKV  (OFF_PW + SZ_PW)           // end = 27525120 elems = 55.1 MB

// Direct-to-LDS 16B DMA; source chunk XOR-swizzled to kill read conflicts.
__device__ __forceinline__ void async16(const bf16* g, bf16* l) {
    __builtin_amdgcn_global_load_lds(
        (const __attribute__((address_space(1))) unsigned int*)g,
        (__attribute__((address_space(3))) unsigned int*)l, 16, 0, 0);
}

// ---------------------------------------------------------------------------
__global__ __launch_bounds__(256) void convert3(
    const float* __restrict__ x, const float* __restrict__ qkvw,
    const float* __restrict__ pw, bf16* __restrict__ ws) {
    const int t = blockIdx.x * 256 + threadIdx.x;
    const int S = gridDim.x * 256;
    for (int i = t; i < SZ_X;    i += S) ws[OFF_X + i]  = (bf16)x[i];
    for (int i = t; i < SZ_QKVW; i += S) ws[OFF_QW + i] = (bf16)qkvw[i];
    for (int i = t; i < SZ_PW;   i += S) ws[OFF_PW + i] = (bf16)pw[i];
}

// ---------------------------------------------------------------------------
// m97-style GEMM: 128x128 tile, BK=64, DMA staging, swizzled LDS (unchanged).
// ---------------------------------------------------------------------------
template <bool HAS_BIAS, typename OutT>
__global__ __launch_bounds__(256) void gemm128(
    const bf16* __restrict__ A, int lda, const bf16* __restrict__ W,
    const float* __restrict__ bias, OutT* __restrict__ C,
    int M, int Nn, int K) {
    __shared__ __align__(16) bf16 As[128 * 64];
    __shared__ __align__(16) bf16 Bs[128 * 64];
    const int tid  = threadIdx.x;
    const int wave = tid >> 6;
    const int lane = tid & 63;
    const int quad = lane >> 4;
    const int l16  = lane & 15;
    const int m0 = blockIdx.y * 128;
    const int n0 = blockIdx.x * 128;
    const int wm = (wave >> 1) * 64;
    const int wn = (wave & 1) * 64;
    const int srow = lane >> 3;
    const int swz  = (lane & 7) ^ srow;

    f32x4 acc[4][4];
#pragma unroll
    for (int i = 0; i < 4; ++i)
#pragma unroll
        for (int j = 0; j < 4; ++j) acc[i][j] = (f32x4){0.f, 0.f, 0.f, 0.f};

    for (int k0 = 0; k0 < K; k0 += 64) {
#pragma unroll
        for (int i = 0; i < 4; ++i) {
            int row = i * 32 + wave * 8 + srow;
            async16(A + (size_t)(m0 + row) * lda + k0 + swz * 8,
                    &As[(i * 32 + wave * 8) * 64]);
            async16(W + (size_t)(n0 + row) * K + k0 + swz * 8,
                    &Bs[(i * 32 + wave * 8) * 64]);
        }
        __syncthreads();
#pragma unroll
        for (int kk = 0; kk < 2; ++kk) {
            const int slot = ((kk * 4 + quad) ^ (l16 & 7)) * 8;
            bf16x8 af[4], bf[4];
#pragma unroll
            for (int mt = 0; mt < 4; ++mt)
                af[mt] = *(const bf16x8*)(&As[(wm + mt * 16 + l16) * 64 + slot]);
#pragma unroll
            for (int nt = 0; nt < 4; ++nt)
                bf[nt] = *(const bf16x8*)(&Bs[(wn + nt * 16 + l16) * 64 + slot]);
#pragma unroll
            for (int mt = 0; mt < 4; ++mt)
#pragma unroll
                for (int nt = 0; nt < 4; ++nt)
                    acc[mt][nt] = __builtin_amdgcn_mfma_f32_16x16x32_bf16(
                        af[mt], bf[nt], acc[mt][nt], 0, 0, 0);
        }
        __syncthreads();
    }
#pragma unroll
    for (int mt = 0; mt < 4; ++mt)
#pragma unroll
        for (int nt = 0; nt < 4; ++nt)
#pragma unroll
            for (int r = 0; r < 4; ++r) {
                int row = m0 + wm + mt * 16 + quad * 4 + r;
                int col = n0 + wn + nt * 16 + l16;
                float v = acc[mt][nt][r];
                if (HAS_BIAS) v += bias[col];
                C[(size_t)row * Nn + col] = (OutT)v;
            }
}

// ---------------------------------------------------------------------------
// Transpose v-slice of qkv [B*N][3C] -> Vt [B*H][D][N]  (unchanged, verified)
// ---------------------------------------------------------------------------
__global__ __launch_bounds__(256) void transpose_v(
    const bf16* __restrict__ qkv, bf16* __restrict__ Vt) {
    __shared__ __align__(16) bf16 Ts[64 * 64];
    const int t = threadIdx.x;
    const int bh = blockIdx.x;
    const int kt = blockIdx.y;
    const int b = bh / HH, h = bh % HH;
    const size_t rs = 3 * CC;
    const bf16* src = qkv + (size_t)b * NN * rs + 2 * CC + h * DD;
    {
        const int keyl = t >> 2;
        const int d0   = (t & 3) * 16;
#pragma unroll
        for (int half = 0; half < 2; ++half) {
            int dd = d0 + half * 8;
            bf16x8 v = *(const bf16x8*)(src + (size_t)(kt * 64 + keyl) * rs + dd);
            int dc = dd >> 3;
            *(bf16x8*)(&Ts[keyl * 64 + ((dc ^ (keyl >> 3)) * 8)]) = v;
        }
    }
    __syncthreads();
#pragma unroll
    for (int p = 0; p < 2; ++p) {
        const int d  = p * 32 + (t >> 3);
        const int kc = (t & 7) * 8;
        bf16x8 v;
#pragma unroll
        for (int j = 0; j < 8; ++j) {
            int key = kc + j;
            v[j] = Ts[key * 64 + (((d >> 3) ^ (key >> 3)) * 8 + (d & 7))];
        }
        *(bf16x8*)(Vt + ((size_t)bh * DD + d) * NN + kt * 64 + kc) = v;
    }
}

// ---------------------------------------------------------------------------
// RMSNorm + RoPE in-place on q,k.  q-rows are additionally scaled by
// CEXP = 0.125*log2(e) in fp32 before the single bf16 rounding, so QK^T
// scores exit the MFMA already in exp2-domain (flash does p = exp2(s), no
// per-element fma, no shift — softmax is shift-invariant and the constant
// cancels in accO/lsum; range |s'| <= 23.1 is safe in bf16/fp32).
// ---------------------------------------------------------------------------
__global__ __launch_bounds__(256) void norm_rope(
    bf16* __restrict__ qkv, const float* __restrict__ cosb,
    const float* __restrict__ sinb, const float* __restrict__ qw,
    const float* __restrict__ kw) {
    const int lane = threadIdx.x & 63;
    const int wave = threadIdx.x >> 6;
    const int job = blockIdx.x * 4 + wave;
    const int h = job % HH;
    const int s = (job / HH) & 1;
    const int bn = job / (2 * HH);
    const int n = bn % NN;

    bf16* row = qkv + (size_t)bn * (3 * CC) + s * CC + h * DD;
    float x = (float)row[lane];
    float ss = x * x;
#pragma unroll
    for (int m = 32; m >= 1; m >>= 1) ss += __shfl_xor(ss, m, 64);
    float r = rsqrtf(ss * (1.0f / 64.0f) + 1e-6f);
    x = x * r * ((s == 0) ? qw[lane] : kw[lane]);
    float xp = __shfl_xor(x, 32, 64);
    int j = lane & 31;
    float c  = cosb[n * 32 + j];
    float si = sinb[n * 32 + j];
    x = (lane < 32) ? (x * c - xp * si) : (x * c + xp * si);
    if (s == 0) x *= 0.18033688f;   // CEXP folded into q (fp32, pre-rounding)
    row[lane] = (bf16)x;
}

// ---------------------------------------------------------------------------
// Flash attention. Round-2 change (T14, async-STAGE split): next tile's K/V
// are loaded into REGISTERS (4x global_load_dwordx4/thread) before computing
// the current tile, then written regs->LDS at the top of the next tile.
// HBM/L2 latency hides under a full tile of MFMA+exp; the old exposed
// issue-DMA -> vmcnt(0)-drain stall is gone.  LDS stays single-buffered
// (34.8 KB -> 4 blocks/CU preserved — round-1's dbuf regression was the
// occupancy loss).  Barrier count unchanged at 2/tile.  No setprio (4-wave
// lockstep blocks = m190 null regime).
// ---------------------------------------------------------------------------
__global__ __launch_bounds__(256) void flash_attn(
    const bf16* __restrict__ qkv, const bf16* __restrict__ Vt,
    bf16* __restrict__ Oqkv) {
    __shared__ __align__(16) bf16 Ks[64 * 64];       // [key][d] swizzled
    __shared__ __align__(16) bf16 Vs[64 * 64];       // [d][key] swizzled
    __shared__ __align__(16) bf16 Ps[4][32 * 72];    // per-wave [q][key], padded
    const int tid  = threadIdx.x;
    const int wave = tid >> 6;
    const int lane = tid & 63;
    const int quad = lane >> 4;
    const int l16  = lane & 15;
    const int r7   = l16 & 7;
    const int bh = blockIdx.x;
    const int qt = blockIdx.y;
    const int b = bh / HH, h = bh % HH;
    const size_t rs = 3 * CC;
    const bf16* Qb  = qkv + (size_t)b * NN * rs + h * DD;
    const bf16* Kb  = Qb + CC;
    const bf16* Vtb = Vt + (size_t)bh * DD * NN;

    const int srow = lane >> 3;
    const int swz  = (lane & 7) ^ srow;

    bf16x8 qf[2][2];
#pragma unroll
    for (int f = 0; f < 2; ++f) {
        const int qrow = qt * 128 + wave * 32 + f * 16 + l16;
#pragma unroll
        for (int hf = 0; hf < 2; ++hf)
            qf[f][hf] = *(const bf16x8*)(Qb + (size_t)qrow * rs + hf * 32 + quad * 8);
    }

    f32x4 accO[2][4];
#pragma unroll
    for (int f = 0; f < 2; ++f)
#pragma unroll
        for (int i = 0; i < 4; ++i) accO[f][i] = (f32x4){0.f, 0.f, 0.f, 0.f};
    float lsum[2] = {0.f, 0.f};

    // per-thread register staging (T14): chunk i covers rows i*32+wave*8+srow;
    // lane's 16B lands at chunk_base + lane*16B (same linear layout + source
    // XOR-swizzle the DMA produced).
    i32x4 stK[2], stV[2];
    // per-lane global sources (match old async16 per-lane addresses)
    const bf16* srcK[2];
    const bf16* srcV[2];
#pragma unroll
    for (int i = 0; i < 2; ++i) {
        int row = i * 32 + wave * 8 + srow;
        srcK[i] = Kb + (size_t)row * rs + swz * 8;
        srcV[i] = Vtb + (size_t)row * NN + swz * 8;
    }

    // prologue: load tile 0 into regs
#pragma unroll
    for (int i = 0; i < 2; ++i) {
        stK[i] = *(const i32x4*)(srcK[i]);
        stV[i] = *(const i32x4*)(srcV[i]);
    }

    for (int kt = 0; kt < NN / 64; ++kt) {
        __syncthreads();   // all waves done reading LDS tile kt-1
        // write staged regs -> LDS (vmcnt wait here was covered by tile kt-1)
#pragma unroll
        for (int i = 0; i < 2; ++i) {
            *(i32x4*)(&Ks[(i * 32 + wave * 8) * 64 + lane * 8]) = stK[i];
            *(i32x4*)(&Vs[(i * 32 + wave * 8) * 64 + lane * 8]) = stV[i];
        }
        __syncthreads();   // tile kt visible to all waves

        // issue NEXT tile's loads; latency hides under this tile's compute
        if (kt < NN / 64 - 1) {
#pragma unroll
            for (int i = 0; i < 2; ++i) {
                stK[i] = *(const i32x4*)(srcK[i] + (size_t)(kt + 1) * 64 * rs);
                stV[i] = *(const i32x4*)(srcV[i] + (kt + 1) * 64);
            }
        }

        // S^T = (Q K^T)^T via swapped operands; scores already exp2-domain
        f32x4 s[2][4];
#pragma unroll
        for (int nt = 0; nt < 4; ++nt) {
            const int row = nt * 16 + l16;
            bf16x8 kf0 = *(const bf16x8*)(&Ks[row * 64 + (quad ^ r7) * 8]);
            bf16x8 kf1 = *(const bf16x8*)(&Ks[row * 64 + ((quad + 4) ^ r7) * 8]);
#pragma unroll
            for (int f = 0; f < 2; ++f) {
                f32x4 z = (f32x4){0.f, 0.f, 0.f, 0.f};
                z = __builtin_amdgcn_mfma_f32_16x16x32_bf16(kf0, qf[f][0], z, 0, 0, 0);
                s[f][nt] = __builtin_amdgcn_mfma_f32_16x16x32_bf16(kf1, qf[f][1], z, 0, 0, 0);
            }
        }

        // p = exp2(s); packed b64 stores (4 consecutive keys per store)
#pragma unroll
        for (int f = 0; f < 2; ++f)
#pragma unroll
            for (int nt = 0; nt < 4; ++nt) {
                bf16x4 pk;
#pragma unroll
                for (int r = 0; r < 4; ++r) {
                    float pv = __builtin_amdgcn_exp2f(s[f][nt][r]);
                    lsum[f] += pv;
                    pk[r] = (bf16)pv;
                }
                *(bf16x4*)(&Ps[wave][(f * 16 + l16) * 72 + nt * 16 + quad * 4]) = pk;
            }
        // Ps wave-private: wave-local DS drain + compiler fence
        __asm__ volatile("s_waitcnt lgkmcnt(0)" ::: "memory");

        bf16x8 pf0[2], pf1[2];
#pragma unroll
        for (int f = 0; f < 2; ++f) {
            pf0[f] = *(const bf16x8*)(&Ps[wave][(f * 16 + l16) * 72 + quad * 8]);
            pf1[f] = *(const bf16x8*)(&Ps[wave][(f * 16 + l16) * 72 + 32 + quad * 8]);
        }
#pragma unroll
        for (int nt = 0; nt < 4; ++nt) {
            const int rowd = nt * 16 + l16;
            bf16x8 vf0 = *(const bf16x8*)(&Vs[rowd * 64 + (quad ^ r7) * 8]);
            bf16x8 vf1 = *(const bf16x8*)(&Vs[rowd * 64 + ((quad + 4) ^ r7) * 8]);
#pragma unroll
            for (int f = 0; f < 2; ++f) {
                accO[f][nt] = __builtin_amdgcn_mfma_f32_16x16x32_bf16(pf0[f], vf0, accO[f][nt], 0, 0, 0);
                accO[f][nt] = __builtin_amdgcn_mfma_f32_16x16x32_bf16(pf1[f], vf1, accO[f][nt], 0, 0, 0);
            }
        }
    }

    // lsum: reduce over the 4 quads sharing l16 (lane's q = f*16+l16)
#pragma unroll
    for (int f = 0; f < 2; ++f) {
        lsum[f] += __shfl_xor(lsum[f], 16, 64);
        lsum[f] += __shfl_xor(lsum[f], 32, 64);
    }

    // epilogue: accO row q = f*16+quad*4+r; fetch 1/lsum from lane quad*4+r
#pragma unroll
    for (int f = 0; f < 2; ++f)
#pragma unroll
        for (int r = 0; r < 4; ++r) {
            float inv = 1.0f / __shfl(lsum[f], quad * 4 + r, 64);
            int n = qt * 128 + wave * 32 + f * 16 + quad * 4 + r;
#pragma unroll
            for (int nt = 0; nt < 4; ++nt) {
                int col = h * DD + nt * 16 + l16;
                Oqkv[(size_t)(b * NN + n) * rs + 2 * CC + col] = (bf16)(accO[f][nt][r] * inv);
            }
        }
}

// ---------------------------------------------------------------------------
extern "C" void kernel_launch(void* const* d_in, const int* in_sizes, int n_in,
                              void* d_out, int out_size, void* d_ws, size_t ws_size,
                              hipStream_t stream) {
    const float* x     = (const float*)d_in[0];
    const float* cosb  = (const float*)d_in[1];
    const float* sinb  = (const float*)d_in[2];
    const float* qkv_w = (const float*)d_in[3];
    const float* qnw   = (const float*)d_in[4];
    const float* knw   = (const float*)d_in[5];
    const float* pw    = (const float*)d_in[6];
    const float* pb    = (const float*)d_in[7];
    float* out = (float*)d_out;

    bf16* ws  = (bf16*)d_ws;
    bf16* xb  = ws + OFF_X;
    bf16* vt  = ws + OFF_VT;   // reuses xb after QKV GEMM
    bf16* qwb = ws + OFF_QW;
    bf16* pwb = ws + OFF_PW;
    bf16* qkv = ws + OFF_QKV;

    const int M = BB * NN;  // 8192

    // 0) cast MFMA operands to bf16
    convert3<<<1024, 256, 0, stream>>>(x, qkv_w, pw, ws);

    // 1) QKV projection -> qkv [B*N][3C] (bf16); 128x128 tiles
    dim3 g1(3 * CC / 128, M / 128);
    gemm128<false, bf16><<<g1, 256, 0, stream>>>(xb, CC, qwb, nullptr, qkv, M, 3 * CC, CC);

    // 2) transpose v-slice -> Vt [B*H][D][N]
    dim3 g2(BB * HH, NN / 64);
    transpose_v<<<g2, 256, 0, stream>>>(qkv, vt);

    // 3) RMSNorm + RoPE in place on q,k (q pre-scaled by CEXP)
    norm_rope<<<(BB * NN * 2 * HH) / 4, 256, 0, stream>>>(qkv, cosb, sinb, qnw, knw);

    // 4) Flash attention -> v-slice of qkv; 128 q-rows, 64-key tiles
    dim3 g4(BB * HH, NN / 128);
    flash_attn<<<g4, 256, 0, stream>>>(qkv, vt, qkv);

    // 5) Output projection (+fp32 bias) -> d_out; A = v-slice, lda = 3C
    dim3 g5(CC / 128, M / 128);
    gemm128<true, float><<<g5, 256, 0, stream>>>(qkv + 2 * CC, 3 * CC, pwb, pb, out, M, CC, CC);
}

// Round 3
// 241.933 us; speedup vs baseline: 1.1293x; 1.0996x over previous
//
#include <hip/hip_runtime.h>
#include <hip/hip_bf16.h>

// Problem constants (B=4, N=2048, C=768, H=12, D=64)
#define BB 4
#define NN 2048
#define CC 768
#define HH 12
#define DD 64

typedef __bf16 bf16;
typedef __attribute__((ext_vector_type(8))) __bf16 bf16x8;
typedef __attribute__((ext_vector_type(4))) __bf16 bf16x4;
typedef __attribute__((ext_vector_type(4))) float f32x4;

// ---- workspace layout (bf16 elems) ----------------------------------------
#define SZ_X    (BB * NN * CC)              // 6291456
#define SZ_QKVW (3 * CC * CC)               // 1769472
#define SZ_PW   (CC * CC)                   // 589824
#define SZ_QKV  ((size_t)BB * NN * 3 * CC)  // 18874368

#define OFF_X    0
#define OFF_VT   0                          // aliases xb (x dead after QKV GEMM)
#define OFF_QW   (OFF_X + SZ_X)
#define OFF_PW   (OFF_QW + SZ_QKVW)
#define OFF_QKV  (OFF_PW + SZ_PW)           // end = 27525120 elems = 55.1 MB

// Direct-to-LDS 16B DMA; source chunk XOR-swizzled to kill read conflicts.
__device__ __forceinline__ void async16(const bf16* g, bf16* l) {
    __builtin_amdgcn_global_load_lds(
        (const __attribute__((address_space(1))) unsigned int*)g,
        (__attribute__((address_space(3))) unsigned int*)l, 16, 0, 0);
}

// ---------------------------------------------------------------------------
// Vectorized f32 -> bf16 casts: 8 elems/thread (2x f32x4 load, 1x bf16x8 store).
// All three sizes are divisible by 8; all base offsets are 16B-aligned.
// ---------------------------------------------------------------------------
__device__ __forceinline__ void cast8(const float* __restrict__ src,
                                      bf16* __restrict__ dst, int i) {
    f32x4 a = ((const f32x4*)src)[2 * i];
    f32x4 b = ((const f32x4*)src)[2 * i + 1];
    bf16x8 o;
#pragma unroll
    for (int j = 0; j < 4; ++j) { o[j] = (bf16)a[j]; o[j + 4] = (bf16)b[j]; }
    ((bf16x8*)dst)[i] = o;
}

__global__ __launch_bounds__(256) void convert3(
    const float* __restrict__ x, const float* __restrict__ qkvw,
    const float* __restrict__ pw, bf16* __restrict__ ws) {
    const int t = blockIdx.x * 256 + threadIdx.x;
    const int S = gridDim.x * 256;
    for (int i = t; i < SZ_X / 8;    i += S) cast8(x,    ws + OFF_X,  i);
    for (int i = t; i < SZ_QKVW / 8; i += S) cast8(qkvw, ws + OFF_QW, i);
    for (int i = t; i < SZ_PW / 8;   i += S) cast8(pw,   ws + OFF_PW, i);
}

// ---------------------------------------------------------------------------
// m97-style GEMM: 128x128 tile, BK=64, DMA staging, swizzled LDS (unchanged).
// ---------------------------------------------------------------------------
template <bool HAS_BIAS, typename OutT>
__global__ __launch_bounds__(256) void gemm128(
    const bf16* __restrict__ A, int lda, const bf16* __restrict__ W,
    const float* __restrict__ bias, OutT* __restrict__ C,
    int M, int Nn, int K) {
    __shared__ __align__(16) bf16 As[128 * 64];
    __shared__ __align__(16) bf16 Bs[128 * 64];
    const int tid  = threadIdx.x;
    const int wave = tid >> 6;
    const int lane = tid & 63;
    const int quad = lane >> 4;
    const int l16  = lane & 15;
    const int m0 = blockIdx.y * 128;
    const int n0 = blockIdx.x * 128;
    const int wm = (wave >> 1) * 64;
    const int wn = (wave & 1) * 64;
    const int srow = lane >> 3;
    const int swz  = (lane & 7) ^ srow;

    f32x4 acc[4][4];
#pragma unroll
    for (int i = 0; i < 4; ++i)
#pragma unroll
        for (int j = 0; j < 4; ++j) acc[i][j] = (f32x4){0.f, 0.f, 0.f, 0.f};

    for (int k0 = 0; k0 < K; k0 += 64) {
#pragma unroll
        for (int i = 0; i < 4; ++i) {
            int row = i * 32 + wave * 8 + srow;
            async16(A + (size_t)(m0 + row) * lda + k0 + swz * 8,
                    &As[(i * 32 + wave * 8) * 64]);
            async16(W + (size_t)(n0 + row) * K + k0 + swz * 8,
                    &Bs[(i * 32 + wave * 8) * 64]);
        }
        __syncthreads();
#pragma unroll
        for (int kk = 0; kk < 2; ++kk) {
            const int slot = ((kk * 4 + quad) ^ (l16 & 7)) * 8;
            bf16x8 af[4], bf[4];
#pragma unroll
            for (int mt = 0; mt < 4; ++mt)
                af[mt] = *(const bf16x8*)(&As[(wm + mt * 16 + l16) * 64 + slot]);
#pragma unroll
            for (int nt = 0; nt < 4; ++nt)
                bf[nt] = *(const bf16x8*)(&Bs[(wn + nt * 16 + l16) * 64 + slot]);
#pragma unroll
            for (int mt = 0; mt < 4; ++mt)
#pragma unroll
                for (int nt = 0; nt < 4; ++nt)
                    acc[mt][nt] = __builtin_amdgcn_mfma_f32_16x16x32_bf16(
                        af[mt], bf[nt], acc[mt][nt], 0, 0, 0);
        }
        __syncthreads();
    }
#pragma unroll
    for (int mt = 0; mt < 4; ++mt)
#pragma unroll
        for (int nt = 0; nt < 4; ++nt)
#pragma unroll
            for (int r = 0; r < 4; ++r) {
                int row = m0 + wm + mt * 16 + quad * 4 + r;
                int col = n0 + wn + nt * 16 + l16;
                float v = acc[mt][nt][r];
                if (HAS_BIAS) v += bias[col];
                C[(size_t)row * Nn + col] = (OutT)v;
            }
}

// ---------------------------------------------------------------------------
// Transpose v-slice of qkv [B*N][3C] -> Vt [B*H][D][N]  (unchanged, verified)
// ---------------------------------------------------------------------------
__global__ __launch_bounds__(256) void transpose_v(
    const bf16* __restrict__ qkv, bf16* __restrict__ Vt) {
    __shared__ __align__(16) bf16 Ts[64 * 64];
    const int t = threadIdx.x;
    const int bh = blockIdx.x;
    const int kt = blockIdx.y;
    const int b = bh / HH, h = bh % HH;
    const size_t rs = 3 * CC;
    const bf16* src = qkv + (size_t)b * NN * rs + 2 * CC + h * DD;
    {
        const int keyl = t >> 2;
        const int d0   = (t & 3) * 16;
#pragma unroll
        for (int half = 0; half < 2; ++half) {
            int dd = d0 + half * 8;
            bf16x8 v = *(const bf16x8*)(src + (size_t)(kt * 64 + keyl) * rs + dd);
            int dc = dd >> 3;
            *(bf16x8*)(&Ts[keyl * 64 + ((dc ^ (keyl >> 3)) * 8)]) = v;
        }
    }
    __syncthreads();
#pragma unroll
    for (int p = 0; p < 2; ++p) {
        const int d  = p * 32 + (t >> 3);
        const int kc = (t & 7) * 8;
        bf16x8 v;
#pragma unroll
        for (int j = 0; j < 8; ++j) {
            int key = kc + j;
            v[j] = Ts[key * 64 + (((d >> 3) ^ (key >> 3)) * 8 + (d & 7))];
        }
        *(bf16x8*)(Vt + ((size_t)bh * DD + d) * NN + kt * 64 + kc) = v;
    }
}

// ---------------------------------------------------------------------------
// RMSNorm + RoPE in-place on q,k.  Rewritten: 8 rows per wave (was 1), 16B
// vector loads/stores.  Lane l = (row gr = l>>3, slot sl = l&7); each lane
// holds elems d = sl*8 .. sl*8+7 of its row.  RMS reduce over the 8 lanes of
// a row (shfl_xor 1/2/4).  RoPE partner d+-32 lives at lane l^4 (slot^4), so
// one shfl_xor(,4) per element swaps halves.  cos/sin index j = d&31 =
// (sl&3)*8 + j.  Semantics identical to the verified scalar version,
// including the CEXP = 0.125*log2(e) fold into q (fp32, pre-rounding).
// 8 consecutive bn per wave share (s,h); BB*NN divisible by 8.
// ---------------------------------------------------------------------------
__global__ __launch_bounds__(256) void norm_rope(
    bf16* __restrict__ qkv, const float* __restrict__ cosb,
    const float* __restrict__ sinb, const float* __restrict__ qw,
    const float* __restrict__ kw) {
    const int lane = threadIdx.x & 63;
    const int wave = threadIdx.x >> 6;
    const int job = blockIdx.x * 4 + wave;      // 0 .. 2*HH*(BB*NN/8)-1
    const int h = job % HH;
    const int s = (job / HH) % 2;
    const int g = job / (2 * HH);               // row-group of 8 bn's
    const int gr = lane >> 3;                   // row within group
    const int sl = lane & 7;                    // 16B slot within row
    const int bn = g * 8 + gr;
    const int n  = bn & (NN - 1);

    bf16* row = qkv + (size_t)bn * (3 * CC) + s * CC + h * DD + sl * 8;
    bf16x8 v = *(const bf16x8*)row;
    float x[8];
    float ss = 0.f;
#pragma unroll
    for (int j = 0; j < 8; ++j) { x[j] = (float)v[j]; ss += x[j] * x[j]; }
    // reduce over the 8 lanes holding this row
    ss += __shfl_xor(ss, 1, 64);
    ss += __shfl_xor(ss, 2, 64);
    ss += __shfl_xor(ss, 4, 64);
    float r = rsqrtf(ss * (1.0f / 64.0f) + 1e-6f);

    const float* wp = ((s == 0) ? qw : kw) + sl * 8;
    f32x4 w0 = *(const f32x4*)(wp);
    f32x4 w1 = *(const f32x4*)(wp + 4);
#pragma unroll
    for (int j = 0; j < 4; ++j) { x[j] *= r * w0[j]; x[j + 4] *= r * w1[j]; }

    // RoPE: partner element (d +- 32) sits in lane l^4, same slot index j
    float xp[8];
#pragma unroll
    for (int j = 0; j < 8; ++j) xp[j] = __shfl_xor(x[j], 4, 64);

    const int jb = (sl & 3) * 8;                // j-base = d & 31 for this slot
    f32x4 c0 = *(const f32x4*)(cosb + n * 32 + jb);
    f32x4 c1 = *(const f32x4*)(cosb + n * 32 + jb + 4);
    f32x4 s0 = *(const f32x4*)(sinb + n * 32 + jb);
    f32x4 s1 = *(const f32x4*)(sinb + n * 32 + jb + 4);
    const float sgn = (sl < 4) ? -1.f : 1.f;    // d<32: x*c - xp*si ; else +
    float y[8];
#pragma unroll
    for (int j = 0; j < 4; ++j) {
        y[j]     = x[j]     * c0[j] + sgn * xp[j]     * s0[j];
        y[j + 4] = x[j + 4] * c1[j] + sgn * xp[j + 4] * s1[j];
    }
    const float qs = (s == 0) ? 0.18033688f : 1.0f;  // CEXP folded into q
    bf16x8 o;
#pragma unroll
    for (int j = 0; j < 8; ++j) o[j] = (bf16)(y[j] * qs);
    *(bf16x8*)row = o;
}

// ---------------------------------------------------------------------------
// Flash attention — round-0 structure restored verbatim (best measured:
// 76.6us, MfmaUtil 27%, 4 blocks/CU).  Rounds 1-2 proved both LDS-dbuf and
// reg-staged pipelining lose to the implicit inter-block TLP overlap here.
// ---------------------------------------------------------------------------
__global__ __launch_bounds__(256) void flash_attn(
    const bf16* __restrict__ qkv, const bf16* __restrict__ Vt,
    bf16* __restrict__ Oqkv) {
    __shared__ __align__(16) bf16 Ks[64 * 64];       // [key][d] swizzled
    __shared__ __align__(16) bf16 Vs[64 * 64];       // [d][key] swizzled
    __shared__ __align__(16) bf16 Ps[4][32 * 72];    // per-wave [q][key], padded
    const int tid  = threadIdx.x;
    const int wave = tid >> 6;
    const int lane = tid & 63;
    const int quad = lane >> 4;
    const int l16  = lane & 15;
    const int r7   = l16 & 7;
    const int bh = blockIdx.x;
    const int qt = blockIdx.y;
    const int b = bh / HH, h = bh % HH;
    const size_t rs = 3 * CC;
    const bf16* Qb  = qkv + (size_t)b * NN * rs + h * DD;
    const bf16* Kb  = Qb + CC;
    const bf16* Vtb = Vt + (size_t)bh * DD * NN;

    bf16x8 qf[2][2];
#pragma unroll
    for (int f = 0; f < 2; ++f) {
        const int qrow = qt * 128 + wave * 32 + f * 16 + l16;
#pragma unroll
        for (int hf = 0; hf < 2; ++hf)
            qf[f][hf] = *(const bf16x8*)(Qb + (size_t)qrow * rs + hf * 32 + quad * 8);
    }

    f32x4 accO[2][4];
#pragma unroll
    for (int f = 0; f < 2; ++f)
#pragma unroll
        for (int i = 0; i < 4; ++i) accO[f][i] = (f32x4){0.f, 0.f, 0.f, 0.f};
    float lsum[2] = {0.f, 0.f};

    const int srow = lane >> 3;
    const int swz  = (lane & 7) ^ srow;

    for (int kt = 0; kt < NN / 64; ++kt) {
        // stage 64 K-rows + 64 V^T d-rows (2 DMA issues each)
#pragma unroll
        for (int i = 0; i < 2; ++i) {
            int row = i * 32 + wave * 8 + srow;
            async16(Kb + (size_t)(kt * 64 + row) * rs + swz * 8,
                    &Ks[(i * 32 + wave * 8) * 64]);
            async16(Vtb + (size_t)row * NN + kt * 64 + swz * 8,
                    &Vs[(i * 32 + wave * 8) * 64]);
        }
        __syncthreads();

        // S^T = (Q K^T)^T via swapped operands; scores already exp2-domain
        f32x4 s[2][4];
#pragma unroll
        for (int nt = 0; nt < 4; ++nt) {
            const int row = nt * 16 + l16;
            bf16x8 kf0 = *(const bf16x8*)(&Ks[row * 64 + (quad ^ r7) * 8]);
            bf16x8 kf1 = *(const bf16x8*)(&Ks[row * 64 + ((quad + 4) ^ r7) * 8]);
#pragma unroll
            for (int f = 0; f < 2; ++f) {
                f32x4 z = (f32x4){0.f, 0.f, 0.f, 0.f};
                z = __builtin_amdgcn_mfma_f32_16x16x32_bf16(kf0, qf[f][0], z, 0, 0, 0);
                s[f][nt] = __builtin_amdgcn_mfma_f32_16x16x32_bf16(kf1, qf[f][1], z, 0, 0, 0);
            }
        }

        // p = exp2(s); packed b64 stores (4 consecutive keys per store)
#pragma unroll
        for (int f = 0; f < 2; ++f)
#pragma unroll
            for (int nt = 0; nt < 4; ++nt) {
                bf16x4 pk;
#pragma unroll
                for (int r = 0; r < 4; ++r) {
                    float pv = __builtin_amdgcn_exp2f(s[f][nt][r]);
                    lsum[f] += pv;
                    pk[r] = (bf16)pv;
                }
                *(bf16x4*)(&Ps[wave][(f * 16 + l16) * 72 + nt * 16 + quad * 4]) = pk;
            }
        // Ps wave-private: wave-local DS drain + compiler fence
        __asm__ volatile("s_waitcnt lgkmcnt(0)" ::: "memory");

        bf16x8 pf0[2], pf1[2];
#pragma unroll
        for (int f = 0; f < 2; ++f) {
            pf0[f] = *(const bf16x8*)(&Ps[wave][(f * 16 + l16) * 72 + quad * 8]);
            pf1[f] = *(const bf16x8*)(&Ps[wave][(f * 16 + l16) * 72 + 32 + quad * 8]);
        }
#pragma unroll
        for (int nt = 0; nt < 4; ++nt) {
            const int rowd = nt * 16 + l16;
            bf16x8 vf0 = *(const bf16x8*)(&Vs[rowd * 64 + (quad ^ r7) * 8]);
            bf16x8 vf1 = *(const bf16x8*)(&Vs[rowd * 64 + ((quad + 4) ^ r7) * 8]);
#pragma unroll
            for (int f = 0; f < 2; ++f) {
                accO[f][nt] = __builtin_amdgcn_mfma_f32_16x16x32_bf16(pf0[f], vf0, accO[f][nt], 0, 0, 0);
                accO[f][nt] = __builtin_amdgcn_mfma_f32_16x16x32_bf16(pf1[f], vf1, accO[f][nt], 0, 0, 0);
            }
        }
        __syncthreads();
    }

    // lsum: reduce over the 4 quads sharing l16 (lane's q = f*16+l16)
#pragma unroll
    for (int f = 0; f < 2; ++f) {
        lsum[f] += __shfl_xor(lsum[f], 16, 64);
        lsum[f] += __shfl_xor(lsum[f], 32, 64);
    }

    // epilogue: accO row q = f*16+quad*4+r; fetch 1/lsum from lane quad*4+r
#pragma unroll
    for (int f = 0; f < 2; ++f)
#pragma unroll
        for (int r = 0; r < 4; ++r) {
            float inv = 1.0f / __shfl(lsum[f], quad * 4 + r, 64);
            int n = qt * 128 + wave * 32 + f * 16 + quad * 4 + r;
#pragma unroll
            for (int nt = 0; nt < 4; ++nt) {
                int col = h * DD + nt * 16 + l16;
                Oqkv[(size_t)(b * NN + n) * rs + 2 * CC + col] = (bf16)(accO[f][nt][r] * inv);
            }
        }
}

// ---------------------------------------------------------------------------
extern "C" void kernel_launch(void* const* d_in, const int* in_sizes, int n_in,
                              void* d_out, int out_size, void* d_ws, size_t ws_size,
                              hipStream_t stream) {
    const float* x     = (const float*)d_in[0];
    const float* cosb  = (const float*)d_in[1];
    const float* sinb  = (const float*)d_in[2];
    const float* qkv_w = (const float*)d_in[3];
    const float* qnw   = (const float*)d_in[4];
    const float* knw   = (const float*)d_in[5];
    const float* pw    = (const float*)d_in[6];
    const float* pb    = (const float*)d_in[7];
    float* out = (float*)d_out;

    bf16* ws  = (bf16*)d_ws;
    bf16* xb  = ws + OFF_X;
    bf16* vt  = ws + OFF_VT;   // reuses xb after QKV GEMM
    bf16* qwb = ws + OFF_QW;
    bf16* pwb = ws + OFF_PW;
    bf16* qkv = ws + OFF_QKV;

    const int M = BB * NN;  // 8192

    // 0) cast MFMA operands to bf16 (vectorized 8/thread)
    convert3<<<1024, 256, 0, stream>>>(x, qkv_w, pw, ws);

    // 1) QKV projection -> qkv [B*N][3C] (bf16); 128x128 tiles
    dim3 g1(3 * CC / 128, M / 128);
    gemm128<false, bf16><<<g1, 256, 0, stream>>>(xb, CC, qwb, nullptr, qkv, M, 3 * CC, CC);

    // 2) transpose v-slice -> Vt [B*H][D][N]
    dim3 g2(BB * HH, NN / 64);
    transpose_v<<<g2, 256, 0, stream>>>(qkv, vt);

    // 3) RMSNorm + RoPE in place on q,k (8 rows/wave; q pre-scaled by CEXP)
    norm_rope<<<(2 * HH * (BB * NN / 8)) / 4, 256, 0, stream>>>(qkv, cosb, sinb, qnw, knw);

    // 4) Flash attention -> v-slice of qkv; 128 q-rows, 64-key tiles
    dim3 g4(BB * HH, NN / 128);
    flash_attn<<<g4, 256, 0, stream>>>(qkv, vt, qkv);

    // 5) Output projection (+fp32 bias) -> d_out; A = v-slice, lda = 3C
    dim3 g5(CC / 128, M / 128);
    gemm128<true, float><<<g5, 256, 0, stream>>>(qkv + 2 * CC, 3 * CC, pwb, pb, out, M, CC, CC);
}

// Round 4
// 240.768 us; speedup vs baseline: 1.1348x; 1.0048x over previous
//
#include <hip/hip_runtime.h>
#include <hip/hip_bf16.h>

// Problem constants (B=4, N=2048, C=768, H=12, D=64)
#define BB 4
#define NN 2048
#define CC 768
#define HH 12
#define DD 64

typedef __bf16 bf16;
typedef __attribute__((ext_vector_type(8))) __bf16 bf16x8;
typedef __attribute__((ext_vector_type(4))) __bf16 bf16x4;
typedef __attribute__((ext_vector_type(4))) float f32x4;

// ---- workspace layout (bf16 elems) ----------------------------------------
#define SZ_X    (BB * NN * CC)              // 6291456
#define SZ_QKVW (3 * CC * CC)               // 1769472
#define SZ_PW   (CC * CC)                   // 589824
#define SZ_QKV  ((size_t)BB * NN * 3 * CC)  // 18874368

#define OFF_X    0
#define OFF_VT   0                          // aliases xb (x dead after QKV GEMM)
#define OFF_QW   (OFF_X + SZ_X)
#define OFF_PW   (OFF_QW + SZ_QKVW)
#define OFF_QKV  (OFF_PW + SZ_PW)           // end = 27525120 elems = 55.1 MB

// Direct-to-LDS 16B DMA; source chunk XOR-swizzled to kill read conflicts.
__device__ __forceinline__ void async16(const bf16* g, bf16* l) {
    __builtin_amdgcn_global_load_lds(
        (const __attribute__((address_space(1))) unsigned int*)g,
        (__attribute__((address_space(3))) unsigned int*)l, 16, 0, 0);
}

// ---------------------------------------------------------------------------
// Vectorized f32 -> bf16 casts: 8 elems/thread (2x f32x4 load, 1x bf16x8 store).
// ---------------------------------------------------------------------------
__device__ __forceinline__ void cast8(const float* __restrict__ src,
                                      bf16* __restrict__ dst, int i) {
    f32x4 a = ((const f32x4*)src)[2 * i];
    f32x4 b = ((const f32x4*)src)[2 * i + 1];
    bf16x8 o;
#pragma unroll
    for (int j = 0; j < 4; ++j) { o[j] = (bf16)a[j]; o[j + 4] = (bf16)b[j]; }
    ((bf16x8*)dst)[i] = o;
}

__global__ __launch_bounds__(256) void convert3(
    const float* __restrict__ x, const float* __restrict__ qkvw,
    const float* __restrict__ pw, bf16* __restrict__ ws) {
    const int t = blockIdx.x * 256 + threadIdx.x;
    const int S = gridDim.x * 256;
    for (int i = t; i < SZ_X / 8;    i += S) cast8(x,    ws + OFF_X,  i);
    for (int i = t; i < SZ_QKVW / 8; i += S) cast8(qkvw, ws + OFF_QW, i);
    for (int i = t; i < SZ_PW / 8;   i += S) cast8(pw,   ws + OFF_PW, i);
}

// ---------------------------------------------------------------------------
// QKV GEMM with FUSED RMSNorm+RoPE epilogue (new this round).
// 128x128 tile, BK=64, DMA staging, swizzled LDS — main loop identical to the
// verified gemm128.  Epilogue: each wave's 64-col span (wn 64-wide, aligned)
// is exactly ONE head of q, k, or v.  For fixed (mt,r) the 16 lanes of a quad
// hold one full row's 64 head elems (d = nt*16+l16, 4 per lane):
//   - RMS: per-lane 4-term sum of squares + shfl_xor(1,2,4,8) over the quad's
//     16-lane group -> full-row sum; rsqrt on the fp32 accumulator (closer to
//     the f32 reference than the old bf16 round-trip).
//   - RoPE: partner d+-32 is register nt^2 IN THE SAME LANE (no shuffle);
//     j = d&31 = (nt&1)*16+l16 -> cos/sin loads coalesced per quad.
//   - q rows additionally scaled by CEXP = 0.125*log2(e) (exp2-domain fold,
//     unchanged semantics vs the deleted norm_rope kernel).
// v-sector waves take the plain store path (wave-uniform branch).
// ---------------------------------------------------------------------------
__global__ __launch_bounds__(256) void gemm_qkv(
    const bf16* __restrict__ A, const bf16* __restrict__ W,
    bf16* __restrict__ C, const float* __restrict__ cosb,
    const float* __restrict__ sinb, const float* __restrict__ qw,
    const float* __restrict__ kw) {
    __shared__ __align__(16) bf16 As[128 * 64];
    __shared__ __align__(16) bf16 Bs[128 * 64];
    const int tid  = threadIdx.x;
    const int wave = tid >> 6;
    const int lane = tid & 63;
    const int quad = lane >> 4;
    const int l16  = lane & 15;
    const int m0 = blockIdx.y * 128;
    const int n0 = blockIdx.x * 128;
    const int wm = (wave >> 1) * 64;
    const int wn = (wave & 1) * 64;
    const int srow = lane >> 3;
    const int swz  = (lane & 7) ^ srow;
    const int K = CC;
    const int Nn = 3 * CC;

    f32x4 acc[4][4];
#pragma unroll
    for (int i = 0; i < 4; ++i)
#pragma unroll
        for (int j = 0; j < 4; ++j) acc[i][j] = (f32x4){0.f, 0.f, 0.f, 0.f};

    for (int k0 = 0; k0 < K; k0 += 64) {
#pragma unroll
        for (int i = 0; i < 4; ++i) {
            int row = i * 32 + wave * 8 + srow;
            async16(A + (size_t)(m0 + row) * CC + k0 + swz * 8,
                    &As[(i * 32 + wave * 8) * 64]);
            async16(W + (size_t)(n0 + row) * K + k0 + swz * 8,
                    &Bs[(i * 32 + wave * 8) * 64]);
        }
        __syncthreads();
#pragma unroll
        for (int kk = 0; kk < 2; ++kk) {
            const int slot = ((kk * 4 + quad) ^ (l16 & 7)) * 8;
            bf16x8 af[4], bf[4];
#pragma unroll
            for (int mt = 0; mt < 4; ++mt)
                af[mt] = *(const bf16x8*)(&As[(wm + mt * 16 + l16) * 64 + slot]);
#pragma unroll
            for (int nt = 0; nt < 4; ++nt)
                bf[nt] = *(const bf16x8*)(&Bs[(wn + nt * 16 + l16) * 64 + slot]);
#pragma unroll
            for (int mt = 0; mt < 4; ++mt)
#pragma unroll
                for (int nt = 0; nt < 4; ++nt)
                    acc[mt][nt] = __builtin_amdgcn_mfma_f32_16x16x32_bf16(
                        af[mt], bf[nt], acc[mt][nt], 0, 0, 0);
        }
        __syncthreads();
    }

    const int colblk = n0 + wn;          // 64-aligned; one head of q/k/v
    const int sector = colblk / CC;      // 0=q, 1=k, 2=v
    if (sector == 2) {
        // v: plain stores (consumed by transpose_v / proj path)
#pragma unroll
        for (int mt = 0; mt < 4; ++mt)
#pragma unroll
            for (int nt = 0; nt < 4; ++nt)
#pragma unroll
                for (int r = 0; r < 4; ++r) {
                    int row = m0 + wm + mt * 16 + quad * 4 + r;
                    int col = colblk + nt * 16 + l16;
                    C[(size_t)row * Nn + col] = (bf16)acc[mt][nt][r];
                }
    } else {
        const float* wp = (sector == 0) ? qw : kw;
        const float qs = (sector == 0) ? 0.18033688f : 1.0f;  // CEXP fold
        float wv[4];
#pragma unroll
        for (int nt = 0; nt < 4; ++nt) wv[nt] = wp[nt * 16 + l16];
#pragma unroll
        for (int mt = 0; mt < 4; ++mt)
#pragma unroll
            for (int r = 0; r < 4; ++r) {
                const int row = m0 + wm + mt * 16 + quad * 4 + r;
                const int n   = row & (NN - 1);
                float v[4];
#pragma unroll
                for (int nt = 0; nt < 4; ++nt) v[nt] = acc[mt][nt][r];
                float ss = v[0] * v[0] + v[1] * v[1] + v[2] * v[2] + v[3] * v[3];
                ss += __shfl_xor(ss, 1, 64);
                ss += __shfl_xor(ss, 2, 64);
                ss += __shfl_xor(ss, 4, 64);
                ss += __shfl_xor(ss, 8, 64);
                const float rn = rsqrtf(ss * (1.0f / 64.0f) + 1e-6f);
#pragma unroll
                for (int nt = 0; nt < 4; ++nt) v[nt] *= rn * wv[nt];
                // RoPE: d = nt*16+l16; partner d+-32 = reg nt^2; j = d&31
                const float c0 = cosb[n * 32 + l16];
                const float c1 = cosb[n * 32 + 16 + l16];
                const float s0 = sinb[n * 32 + l16];
                const float s1 = sinb[n * 32 + 16 + l16];
                float y[4];
                y[0] = v[0] * c0 - v[2] * s0;
                y[1] = v[1] * c1 - v[3] * s1;
                y[2] = v[2] * c0 + v[0] * s0;
                y[3] = v[3] * c1 + v[1] * s1;
#pragma unroll
                for (int nt = 0; nt < 4; ++nt) {
                    int col = colblk + nt * 16 + l16;
                    C[(size_t)row * Nn + col] = (bf16)(y[nt] * qs);
                }
            }
    }
}

// ---------------------------------------------------------------------------
// m97-style GEMM: 128x128 tile, BK=64, DMA staging, swizzled LDS (unchanged).
// Used for the output projection only.
// ---------------------------------------------------------------------------
template <bool HAS_BIAS, typename OutT>
__global__ __launch_bounds__(256) void gemm128(
    const bf16* __restrict__ A, int lda, const bf16* __restrict__ W,
    const float* __restrict__ bias, OutT* __restrict__ C,
    int M, int Nn, int K) {
    __shared__ __align__(16) bf16 As[128 * 64];
    __shared__ __align__(16) bf16 Bs[128 * 64];
    const int tid  = threadIdx.x;
    const int wave = tid >> 6;
    const int lane = tid & 63;
    const int quad = lane >> 4;
    const int l16  = lane & 15;
    const int m0 = blockIdx.y * 128;
    const int n0 = blockIdx.x * 128;
    const int wm = (wave >> 1) * 64;
    const int wn = (wave & 1) * 64;
    const int srow = lane >> 3;
    const int swz  = (lane & 7) ^ srow;

    f32x4 acc[4][4];
#pragma unroll
    for (int i = 0; i < 4; ++i)
#pragma unroll
        for (int j = 0; j < 4; ++j) acc[i][j] = (f32x4){0.f, 0.f, 0.f, 0.f};

    for (int k0 = 0; k0 < K; k0 += 64) {
#pragma unroll
        for (int i = 0; i < 4; ++i) {
            int row = i * 32 + wave * 8 + srow;
            async16(A + (size_t)(m0 + row) * lda + k0 + swz * 8,
                    &As[(i * 32 + wave * 8) * 64]);
            async16(W + (size_t)(n0 + row) * K + k0 + swz * 8,
                    &Bs[(i * 32 + wave * 8) * 64]);
        }
        __syncthreads();
#pragma unroll
        for (int kk = 0; kk < 2; ++kk) {
            const int slot = ((kk * 4 + quad) ^ (l16 & 7)) * 8;
            bf16x8 af[4], bf[4];
#pragma unroll
            for (int mt = 0; mt < 4; ++mt)
                af[mt] = *(const bf16x8*)(&As[(wm + mt * 16 + l16) * 64 + slot]);
#pragma unroll
            for (int nt = 0; nt < 4; ++nt)
                bf[nt] = *(const bf16x8*)(&Bs[(wn + nt * 16 + l16) * 64 + slot]);
#pragma unroll
            for (int mt = 0; mt < 4; ++mt)
#pragma unroll
                for (int nt = 0; nt < 4; ++nt)
                    acc[mt][nt] = __builtin_amdgcn_mfma_f32_16x16x32_bf16(
                        af[mt], bf[nt], acc[mt][nt], 0, 0, 0);
        }
        __syncthreads();
    }
#pragma unroll
    for (int mt = 0; mt < 4; ++mt)
#pragma unroll
        for (int nt = 0; nt < 4; ++nt)
#pragma unroll
            for (int r = 0; r < 4; ++r) {
                int row = m0 + wm + mt * 16 + quad * 4 + r;
                int col = n0 + wn + nt * 16 + l16;
                float v = acc[mt][nt][r];
                if (HAS_BIAS) v += bias[col];
                C[(size_t)row * Nn + col] = (OutT)v;
            }
}

// ---------------------------------------------------------------------------
// Transpose v-slice of qkv [B*N][3C] -> Vt [B*H][D][N]  (unchanged, verified)
// ---------------------------------------------------------------------------
__global__ __launch_bounds__(256) void transpose_v(
    const bf16* __restrict__ qkv, bf16* __restrict__ Vt) {
    __shared__ __align__(16) bf16 Ts[64 * 64];
    const int t = threadIdx.x;
    const int bh = blockIdx.x;
    const int kt = blockIdx.y;
    const int b = bh / HH, h = bh % HH;
    const size_t rs = 3 * CC;
    const bf16* src = qkv + (size_t)b * NN * rs + 2 * CC + h * DD;
    {
        const int keyl = t >> 2;
        const int d0   = (t & 3) * 16;
#pragma unroll
        for (int half = 0; half < 2; ++half) {
            int dd = d0 + half * 8;
            bf16x8 v = *(const bf16x8*)(src + (size_t)(kt * 64 + keyl) * rs + dd);
            int dc = dd >> 3;
            *(bf16x8*)(&Ts[keyl * 64 + ((dc ^ (keyl >> 3)) * 8)]) = v;
        }
    }
    __syncthreads();
#pragma unroll
    for (int p = 0; p < 2; ++p) {
        const int d  = p * 32 + (t >> 3);
        const int kc = (t & 7) * 8;
        bf16x8 v;
#pragma unroll
        for (int j = 0; j < 8; ++j) {
            int key = kc + j;
            v[j] = Ts[key * 64 + (((d >> 3) ^ (key >> 3)) * 8 + (d & 7))];
        }
        *(bf16x8*)(Vt + ((size_t)bh * DD + d) * NN + kt * 64 + kc) = v;
    }
}

// ---------------------------------------------------------------------------
// Flash attention — round-0 structure (best measured: 76.6us, 4 blocks/CU).
// Rounds 1-2 proved both LDS-dbuf and reg-staged pipelining lose to the
// implicit inter-block TLP overlap here.
// ---------------------------------------------------------------------------
__global__ __launch_bounds__(256) void flash_attn(
    const bf16* __restrict__ qkv, const bf16* __restrict__ Vt,
    bf16* __restrict__ Oqkv) {
    __shared__ __align__(16) bf16 Ks[64 * 64];       // [key][d] swizzled
    __shared__ __align__(16) bf16 Vs[64 * 64];       // [d][key] swizzled
    __shared__ __align__(16) bf16 Ps[4][32 * 72];    // per-wave [q][key], padded
    const int tid  = threadIdx.x;
    const int wave = tid >> 6;
    const int lane = tid & 63;
    const int quad = lane >> 4;
    const int l16  = lane & 15;
    const int r7   = l16 & 7;
    const int bh = blockIdx.x;
    const int qt = blockIdx.y;
    const int b = bh / HH, h = bh % HH;
    const size_t rs = 3 * CC;
    const bf16* Qb  = qkv + (size_t)b * NN * rs + h * DD;
    const bf16* Kb  = Qb + CC;
    const bf16* Vtb = Vt + (size_t)bh * DD * NN;

    bf16x8 qf[2][2];
#pragma unroll
    for (int f = 0; f < 2; ++f) {
        const int qrow = qt * 128 + wave * 32 + f * 16 + l16;
#pragma unroll
        for (int hf = 0; hf < 2; ++hf)
            qf[f][hf] = *(const bf16x8*)(Qb + (size_t)qrow * rs + hf * 32 + quad * 8);
    }

    f32x4 accO[2][4];
#pragma unroll
    for (int f = 0; f < 2; ++f)
#pragma unroll
        for (int i = 0; i < 4; ++i) accO[f][i] = (f32x4){0.f, 0.f, 0.f, 0.f};
    float lsum[2] = {0.f, 0.f};

    const int srow = lane >> 3;
    const int swz  = (lane & 7) ^ srow;

    for (int kt = 0; kt < NN / 64; ++kt) {
        // stage 64 K-rows + 64 V^T d-rows (2 DMA issues each)
#pragma unroll
        for (int i = 0; i < 2; ++i) {
            int row = i * 32 + wave * 8 + srow;
            async16(Kb + (size_t)(kt * 64 + row) * rs + swz * 8,
                    &Ks[(i * 32 + wave * 8) * 64]);
            async16(Vtb + (size_t)row * NN + kt * 64 + swz * 8,
                    &Vs[(i * 32 + wave * 8) * 64]);
        }
        __syncthreads();

        // S^T = (Q K^T)^T via swapped operands; scores already exp2-domain
        f32x4 s[2][4];
#pragma unroll
        for (int nt = 0; nt < 4; ++nt) {
            const int row = nt * 16 + l16;
            bf16x8 kf0 = *(const bf16x8*)(&Ks[row * 64 + (quad ^ r7) * 8]);
            bf16x8 kf1 = *(const bf16x8*)(&Ks[row * 64 + ((quad + 4) ^ r7) * 8]);
#pragma unroll
            for (int f = 0; f < 2; ++f) {
                f32x4 z = (f32x4){0.f, 0.f, 0.f, 0.f};
                z = __builtin_amdgcn_mfma_f32_16x16x32_bf16(kf0, qf[f][0], z, 0, 0, 0);
                s[f][nt] = __builtin_amdgcn_mfma_f32_16x16x32_bf16(kf1, qf[f][1], z, 0, 0, 0);
            }
        }

        // p = exp2(s); packed b64 stores (4 consecutive keys per store)
#pragma unroll
        for (int f = 0; f < 2; ++f)
#pragma unroll
            for (int nt = 0; nt < 4; ++nt) {
                bf16x4 pk;
#pragma unroll
                for (int r = 0; r < 4; ++r) {
                    float pv = __builtin_amdgcn_exp2f(s[f][nt][r]);
                    lsum[f] += pv;
                    pk[r] = (bf16)pv;
                }
                *(bf16x4*)(&Ps[wave][(f * 16 + l16) * 72 + nt * 16 + quad * 4]) = pk;
            }
        // Ps wave-private: wave-local DS drain + compiler fence
        __asm__ volatile("s_waitcnt lgkmcnt(0)" ::: "memory");

        bf16x8 pf0[2], pf1[2];
#pragma unroll
        for (int f = 0; f < 2; ++f) {
            pf0[f] = *(const bf16x8*)(&Ps[wave][(f * 16 + l16) * 72 + quad * 8]);
            pf1[f] = *(const bf16x8*)(&Ps[wave][(f * 16 + l16) * 72 + 32 + quad * 8]);
        }
#pragma unroll
        for (int nt = 0; nt < 4; ++nt) {
            const int rowd = nt * 16 + l16;
            bf16x8 vf0 = *(const bf16x8*)(&Vs[rowd * 64 + (quad ^ r7) * 8]);
            bf16x8 vf1 = *(const bf16x8*)(&Vs[rowd * 64 + ((quad + 4) ^ r7) * 8]);
#pragma unroll
            for (int f = 0; f < 2; ++f) {
                accO[f][nt] = __builtin_amdgcn_mfma_f32_16x16x32_bf16(pf0[f], vf0, accO[f][nt], 0, 0, 0);
                accO[f][nt] = __builtin_amdgcn_mfma_f32_16x16x32_bf16(pf1[f], vf1, accO[f][nt], 0, 0, 0);
            }
        }
        __syncthreads();
    }

    // lsum: reduce over the 4 quads sharing l16 (lane's q = f*16+l16)
#pragma unroll
    for (int f = 0; f < 2; ++f) {
        lsum[f] += __shfl_xor(lsum[f], 16, 64);
        lsum[f] += __shfl_xor(lsum[f], 32, 64);
    }

    // epilogue: accO row q = f*16+quad*4+r; fetch 1/lsum from lane quad*4+r
#pragma unroll
    for (int f = 0; f < 2; ++f)
#pragma unroll
        for (int r = 0; r < 4; ++r) {
            float inv = 1.0f / __shfl(lsum[f], quad * 4 + r, 64);
            int n = qt * 128 + wave * 32 + f * 16 + quad * 4 + r;
#pragma unroll
            for (int nt = 0; nt < 4; ++nt) {
                int col = h * DD + nt * 16 + l16;
                Oqkv[(size_t)(b * NN + n) * rs + 2 * CC + col] = (bf16)(accO[f][nt][r] * inv);
            }
        }
}

// ---------------------------------------------------------------------------
extern "C" void kernel_launch(void* const* d_in, const int* in_sizes, int n_in,
                              void* d_out, int out_size, void* d_ws, size_t ws_size,
                              hipStream_t stream) {
    const float* x     = (const float*)d_in[0];
    const float* cosb  = (const float*)d_in[1];
    const float* sinb  = (const float*)d_in[2];
    const float* qkv_w = (const float*)d_in[3];
    const float* qnw   = (const float*)d_in[4];
    const float* knw   = (const float*)d_in[5];
    const float* pw    = (const float*)d_in[6];
    const float* pb    = (const float*)d_in[7];
    float* out = (float*)d_out;

    bf16* ws  = (bf16*)d_ws;
    bf16* xb  = ws + OFF_X;
    bf16* vt  = ws + OFF_VT;   // reuses xb after QKV GEMM
    bf16* qwb = ws + OFF_QW;
    bf16* pwb = ws + OFF_PW;
    bf16* qkv = ws + OFF_QKV;

    const int M = BB * NN;  // 8192

    // 0) cast MFMA operands to bf16 (vectorized 8/thread)
    convert3<<<1024, 256, 0, stream>>>(x, qkv_w, pw, ws);

    // 1) QKV projection + fused RMSNorm/RoPE/CEXP -> qkv [B*N][3C] (bf16)
    dim3 g1(3 * CC / 128, M / 128);
    gemm_qkv<<<g1, 256, 0, stream>>>(xb, qwb, qkv, cosb, sinb, qnw, knw);

    // 2) transpose v-slice -> Vt [B*H][D][N]
    dim3 g2(BB * HH, NN / 64);
    transpose_v<<<g2, 256, 0, stream>>>(qkv, vt);

    // 3) Flash attention -> v-slice of qkv; 128 q-rows, 64-key tiles
    dim3 g4(BB * HH, NN / 128);
    flash_attn<<<g4, 256, 0, stream>>>(qkv, vt, qkv);

    // 4) Output projection (+fp32 bias) -> d_out; A = v-slice, lda = 3C
    dim3 g5(CC / 128, M / 128);
    gemm128<true, float><<<g5, 256, 0, stream>>>(qkv + 2 * CC, 3 * CC, pwb, pb, out, M, CC, CC);
}

// Round 5
// 231.444 us; speedup vs baseline: 1.1805x; 1.0403x over previous
//
#include <hip/hip_runtime.h>
#include <hip/hip_bf16.h>

// Problem constants (B=4, N=2048, C=768, H=12, D=64)
#define BB 4
#define NN 2048
#define CC 768
#define HH 12
#define DD 64

typedef __bf16 bf16;
typedef __attribute__((ext_vector_type(8))) __bf16 bf16x8;
typedef __attribute__((ext_vector_type(4))) __bf16 bf16x4;
typedef __attribute__((ext_vector_type(4))) float f32x4;

// ---- workspace layout (bf16 elems) ----------------------------------------
#define SZ_X    (BB * NN * CC)              // 6291456
#define SZ_QKVW (3 * CC * CC)               // 1769472
#define SZ_PW   (CC * CC)                   // 589824
#define SZ_QKV  ((size_t)BB * NN * 3 * CC)  // 18874368

#define OFF_X    0
#define OFF_QW   (OFF_X + SZ_X)
#define OFF_PW   (OFF_QW + SZ_QKVW)
#define OFF_QKV  (OFF_PW + SZ_PW)           // end = 27525120 elems = 55.1 MB
// Vt [B*H][D][N] (12.6 MB) lives in d_out (25.2 MB f32 scratch until proj).

// Direct-to-LDS 16B DMA; source chunk XOR-swizzled to kill read conflicts.
__device__ __forceinline__ void async16(const bf16* g, bf16* l) {
    __builtin_amdgcn_global_load_lds(
        (const __attribute__((address_space(1))) unsigned int*)g,
        (__attribute__((address_space(3))) unsigned int*)l, 16, 0, 0);
}

// ---------------------------------------------------------------------------
// Vectorized f32 -> bf16 casts: 8 elems/thread (2x f32x4 load, 1x bf16x8 store).
// ---------------------------------------------------------------------------
__device__ __forceinline__ void cast8(const float* __restrict__ src,
                                      bf16* __restrict__ dst, int i) {
    f32x4 a = ((const f32x4*)src)[2 * i];
    f32x4 b = ((const f32x4*)src)[2 * i + 1];
    bf16x8 o;
#pragma unroll
    for (int j = 0; j < 4; ++j) { o[j] = (bf16)a[j]; o[j + 4] = (bf16)b[j]; }
    ((bf16x8*)dst)[i] = o;
}

__global__ __launch_bounds__(256) void convert3(
    const float* __restrict__ x, const float* __restrict__ qkvw,
    const float* __restrict__ pw, bf16* __restrict__ ws) {
    const int t = blockIdx.x * 256 + threadIdx.x;
    const int S = gridDim.x * 256;
    for (int i = t; i < SZ_X / 8;    i += S) cast8(x,    ws + OFF_X,  i);
    for (int i = t; i < SZ_QKVW / 8; i += S) cast8(qkvw, ws + OFF_QW, i);
    for (int i = t; i < SZ_PW / 8;   i += S) cast8(pw,   ws + OFF_PW, i);
}

// ---------------------------------------------------------------------------
// QKV GEMM with fused RMSNorm+RoPE epilogue (verified round 4).  NEW this
// round: the v-sector epilogue writes DIRECTLY TRANSPOSED to Vt[bh][d][n]
// and skips the qkv store (v-slice of qkv had no other consumer; flash
// overwrites it).  transpose_v kernel deleted.  Layout fact used: for fixed
// (mt,nt), acc[mt][nt][r] r=0..3 are 4 consecutive tokens at one fixed d ->
// one bf16x4 store; quads extend to 32B, mt loop to 128B contiguous.
// ---------------------------------------------------------------------------
__global__ __launch_bounds__(256) void gemm_qkv(
    const bf16* __restrict__ A, const bf16* __restrict__ W,
    bf16* __restrict__ C, bf16* __restrict__ Vt,
    const float* __restrict__ cosb, const float* __restrict__ sinb,
    const float* __restrict__ qw, const float* __restrict__ kw) {
    __shared__ __align__(16) bf16 As[128 * 64];
    __shared__ __align__(16) bf16 Bs[128 * 64];
    const int tid  = threadIdx.x;
    const int wave = tid >> 6;
    const int lane = tid & 63;
    const int quad = lane >> 4;
    const int l16  = lane & 15;
    const int m0 = blockIdx.y * 128;
    const int n0 = blockIdx.x * 128;
    const int wm = (wave >> 1) * 64;
    const int wn = (wave & 1) * 64;
    const int srow = lane >> 3;
    const int swz  = (lane & 7) ^ srow;
    const int K = CC;
    const int Nn = 3 * CC;

    f32x4 acc[4][4];
#pragma unroll
    for (int i = 0; i < 4; ++i)
#pragma unroll
        for (int j = 0; j < 4; ++j) acc[i][j] = (f32x4){0.f, 0.f, 0.f, 0.f};

    for (int k0 = 0; k0 < K; k0 += 64) {
#pragma unroll
        for (int i = 0; i < 4; ++i) {
            int row = i * 32 + wave * 8 + srow;
            async16(A + (size_t)(m0 + row) * CC + k0 + swz * 8,
                    &As[(i * 32 + wave * 8) * 64]);
            async16(W + (size_t)(n0 + row) * K + k0 + swz * 8,
                    &Bs[(i * 32 + wave * 8) * 64]);
        }
        __syncthreads();
#pragma unroll
        for (int kk = 0; kk < 2; ++kk) {
            const int slot = ((kk * 4 + quad) ^ (l16 & 7)) * 8;
            bf16x8 af[4], bf[4];
#pragma unroll
            for (int mt = 0; mt < 4; ++mt)
                af[mt] = *(const bf16x8*)(&As[(wm + mt * 16 + l16) * 64 + slot]);
#pragma unroll
            for (int nt = 0; nt < 4; ++nt)
                bf[nt] = *(const bf16x8*)(&Bs[(wn + nt * 16 + l16) * 64 + slot]);
#pragma unroll
            for (int mt = 0; mt < 4; ++mt)
#pragma unroll
                for (int nt = 0; nt < 4; ++nt)
                    acc[mt][nt] = __builtin_amdgcn_mfma_f32_16x16x32_bf16(
                        af[mt], bf[nt], acc[mt][nt], 0, 0, 0);
        }
        __syncthreads();
    }

    const int colblk = n0 + wn;          // 64-aligned; one head of q/k/v
    const int sector = colblk / CC;      // 0=q, 1=k, 2=v
    if (sector == 2) {
        // v: transposed store straight to Vt[bh][d][n]; no qkv store.
        const int head = (colblk >> 6) - 24;     // (colblk - 2*CC)/64
        const int btok = m0 + wm;                // first token row of this wave
        const int bh   = (btok >> 11) * HH + head;
        const int nloc = btok & (NN - 1);
#pragma unroll
        for (int nt = 0; nt < 4; ++nt) {
            const int d = nt * 16 + l16;
            bf16* dst = Vt + ((size_t)bh * DD + d) * NN + nloc + quad * 4;
#pragma unroll
            for (int mt = 0; mt < 4; ++mt) {
                bf16x4 pk;
#pragma unroll
                for (int r = 0; r < 4; ++r) pk[r] = (bf16)acc[mt][nt][r];
                *(bf16x4*)(dst + mt * 16) = pk;
            }
        }
    } else {
        const float* wp = (sector == 0) ? qw : kw;
        const float qs = (sector == 0) ? 0.18033688f : 1.0f;  // CEXP fold
        float wv[4];
#pragma unroll
        for (int nt = 0; nt < 4; ++nt) wv[nt] = wp[nt * 16 + l16];
#pragma unroll
        for (int mt = 0; mt < 4; ++mt)
#pragma unroll
            for (int r = 0; r < 4; ++r) {
                const int row = m0 + wm + mt * 16 + quad * 4 + r;
                const int n   = row & (NN - 1);
                float v[4];
#pragma unroll
                for (int nt = 0; nt < 4; ++nt) v[nt] = acc[mt][nt][r];
                float ss = v[0] * v[0] + v[1] * v[1] + v[2] * v[2] + v[3] * v[3];
                ss += __shfl_xor(ss, 1, 64);
                ss += __shfl_xor(ss, 2, 64);
                ss += __shfl_xor(ss, 4, 64);
                ss += __shfl_xor(ss, 8, 64);
                const float rn = rsqrtf(ss * (1.0f / 64.0f) + 1e-6f);
#pragma unroll
                for (int nt = 0; nt < 4; ++nt) v[nt] *= rn * wv[nt];
                // RoPE: d = nt*16+l16; partner d+-32 = reg nt^2; j = d&31
                const float c0 = cosb[n * 32 + l16];
                const float c1 = cosb[n * 32 + 16 + l16];
                const float s0 = sinb[n * 32 + l16];
                const float s1 = sinb[n * 32 + 16 + l16];
                float y[4];
                y[0] = v[0] * c0 - v[2] * s0;
                y[1] = v[1] * c1 - v[3] * s1;
                y[2] = v[2] * c0 + v[0] * s0;
                y[3] = v[3] * c1 + v[1] * s1;
#pragma unroll
                for (int nt = 0; nt < 4; ++nt) {
                    int col = colblk + nt * 16 + l16;
                    C[(size_t)row * Nn + col] = (bf16)(y[nt] * qs);
                }
            }
    }
}

// ---------------------------------------------------------------------------
// Output projection GEMM, retiled 128x64 (was 128x128) so grid = 768 blocks
// = exactly 3 blocks/CU (old 384 = 1.5/CU wave-quantized to 2 block-waves).
// Same verified staging/swizzle/MFMA pattern; B-side halved; LDS 24 KB.
// ---------------------------------------------------------------------------
__global__ __launch_bounds__(256) void gemm_proj(
    const bf16* __restrict__ A, const bf16* __restrict__ W,
    const float* __restrict__ bias, float* __restrict__ C) {
    __shared__ __align__(16) bf16 As[128 * 64];
    __shared__ __align__(16) bf16 Bs[64 * 64];
    const int tid  = threadIdx.x;
    const int wave = tid >> 6;
    const int lane = tid & 63;
    const int quad = lane >> 4;
    const int l16  = lane & 15;
    const int m0 = blockIdx.y * 128;
    const int n0 = blockIdx.x * 64;
    const int wm = (wave >> 1) * 64;
    const int wn = (wave & 1) * 32;
    const int srow = lane >> 3;
    const int swz  = (lane & 7) ^ srow;
    const int lda = 3 * CC;                 // A = v-slice of qkv
    const int K = CC;

    f32x4 acc[4][2];
#pragma unroll
    for (int i = 0; i < 4; ++i)
#pragma unroll
        for (int j = 0; j < 2; ++j) acc[i][j] = (f32x4){0.f, 0.f, 0.f, 0.f};

    for (int k0 = 0; k0 < K; k0 += 64) {
#pragma unroll
        for (int i = 0; i < 4; ++i) {
            int row = i * 32 + wave * 8 + srow;
            async16(A + (size_t)(m0 + row) * lda + k0 + swz * 8,
                    &As[(i * 32 + wave * 8) * 64]);
        }
#pragma unroll
        for (int i = 0; i < 2; ++i) {
            int row = i * 32 + wave * 8 + srow;
            async16(W + (size_t)(n0 + row) * K + k0 + swz * 8,
                    &Bs[(i * 32 + wave * 8) * 64]);
        }
        __syncthreads();
#pragma unroll
        for (int kk = 0; kk < 2; ++kk) {
            const int slot = ((kk * 4 + quad) ^ (l16 & 7)) * 8;
            bf16x8 af[4], bf[2];
#pragma unroll
            for (int mt = 0; mt < 4; ++mt)
                af[mt] = *(const bf16x8*)(&As[(wm + mt * 16 + l16) * 64 + slot]);
#pragma unroll
            for (int nt = 0; nt < 2; ++nt)
                bf[nt] = *(const bf16x8*)(&Bs[(wn + nt * 16 + l16) * 64 + slot]);
#pragma unroll
            for (int mt = 0; mt < 4; ++mt)
#pragma unroll
                for (int nt = 0; nt < 2; ++nt)
                    acc[mt][nt] = __builtin_amdgcn_mfma_f32_16x16x32_bf16(
                        af[mt], bf[nt], acc[mt][nt], 0, 0, 0);
        }
        __syncthreads();
    }
#pragma unroll
    for (int mt = 0; mt < 4; ++mt)
#pragma unroll
        for (int nt = 0; nt < 2; ++nt)
#pragma unroll
            for (int r = 0; r < 4; ++r) {
                int row = m0 + wm + mt * 16 + quad * 4 + r;
                int col = n0 + wn + nt * 16 + l16;
                C[(size_t)row * CC + col] = acc[mt][nt][r] + bias[col];
            }
}

// ---------------------------------------------------------------------------
// Flash attention — round-0 structure (best measured: 76.6us, 4 blocks/CU).
// Rounds 1-2 proved both LDS-dbuf and reg-staged pipelining lose to the
// implicit inter-block TLP overlap here.
// ---------------------------------------------------------------------------
__global__ __launch_bounds__(256) void flash_attn(
    const bf16* __restrict__ qkv, const bf16* __restrict__ Vt,
    bf16* __restrict__ Oqkv) {
    __shared__ __align__(16) bf16 Ks[64 * 64];       // [key][d] swizzled
    __shared__ __align__(16) bf16 Vs[64 * 64];       // [d][key] swizzled
    __shared__ __align__(16) bf16 Ps[4][32 * 72];    // per-wave [q][key], padded
    const int tid  = threadIdx.x;
    const int wave = tid >> 6;
    const int lane = tid & 63;
    const int quad = lane >> 4;
    const int l16  = lane & 15;
    const int r7   = l16 & 7;
    const int bh = blockIdx.x;
    const int qt = blockIdx.y;
    const int b = bh / HH, h = bh % HH;
    const size_t rs = 3 * CC;
    const bf16* Qb  = qkv + (size_t)b * NN * rs + h * DD;
    const bf16* Kb  = Qb + CC;
    const bf16* Vtb = Vt + (size_t)bh * DD * NN;

    bf16x8 qf[2][2];
#pragma unroll
    for (int f = 0; f < 2; ++f) {
        const int qrow = qt * 128 + wave * 32 + f * 16 + l16;
#pragma unroll
        for (int hf = 0; hf < 2; ++hf)
            qf[f][hf] = *(const bf16x8*)(Qb + (size_t)qrow * rs + hf * 32 + quad * 8);
    }

    f32x4 accO[2][4];
#pragma unroll
    for (int f = 0; f < 2; ++f)
#pragma unroll
        for (int i = 0; i < 4; ++i) accO[f][i] = (f32x4){0.f, 0.f, 0.f, 0.f};
    float lsum[2] = {0.f, 0.f};

    const int srow = lane >> 3;
    const int swz  = (lane & 7) ^ srow;

    for (int kt = 0; kt < NN / 64; ++kt) {
        // stage 64 K-rows + 64 V^T d-rows (2 DMA issues each)
#pragma unroll
        for (int i = 0; i < 2; ++i) {
            int row = i * 32 + wave * 8 + srow;
            async16(Kb + (size_t)(kt * 64 + row) * rs + swz * 8,
                    &Ks[(i * 32 + wave * 8) * 64]);
            async16(Vtb + (size_t)row * NN + kt * 64 + swz * 8,
                    &Vs[(i * 32 + wave * 8) * 64]);
        }
        __syncthreads();

        // S^T = (Q K^T)^T via swapped operands; scores already exp2-domain
        f32x4 s[2][4];
#pragma unroll
        for (int nt = 0; nt < 4; ++nt) {
            const int row = nt * 16 + l16;
            bf16x8 kf0 = *(const bf16x8*)(&Ks[row * 64 + (quad ^ r7) * 8]);
            bf16x8 kf1 = *(const bf16x8*)(&Ks[row * 64 + ((quad + 4) ^ r7) * 8]);
#pragma unroll
            for (int f = 0; f < 2; ++f) {
                f32x4 z = (f32x4){0.f, 0.f, 0.f, 0.f};
                z = __builtin_amdgcn_mfma_f32_16x16x32_bf16(kf0, qf[f][0], z, 0, 0, 0);
                s[f][nt] = __builtin_amdgcn_mfma_f32_16x16x32_bf16(kf1, qf[f][1], z, 0, 0, 0);
            }
        }

        // p = exp2(s); packed b64 stores (4 consecutive keys per store)
#pragma unroll
        for (int f = 0; f < 2; ++f)
#pragma unroll
            for (int nt = 0; nt < 4; ++nt) {
                bf16x4 pk;
#pragma unroll
                for (int r = 0; r < 4; ++r) {
                    float pv = __builtin_amdgcn_exp2f(s[f][nt][r]);
                    lsum[f] += pv;
                    pk[r] = (bf16)pv;
                }
                *(bf16x4*)(&Ps[wave][(f * 16 + l16) * 72 + nt * 16 + quad * 4]) = pk;
            }
        // Ps wave-private: wave-local DS drain + compiler fence
        __asm__ volatile("s_waitcnt lgkmcnt(0)" ::: "memory");

        bf16x8 pf0[2], pf1[2];
#pragma unroll
        for (int f = 0; f < 2; ++f) {
            pf0[f] = *(const bf16x8*)(&Ps[wave][(f * 16 + l16) * 72 + quad * 8]);
            pf1[f] = *(const bf16x8*)(&Ps[wave][(f * 16 + l16) * 72 + 32 + quad * 8]);
        }
#pragma unroll
        for (int nt = 0; nt < 4; ++nt) {
            const int rowd = nt * 16 + l16;
            bf16x8 vf0 = *(const bf16x8*)(&Vs[rowd * 64 + (quad ^ r7) * 8]);
            bf16x8 vf1 = *(const bf16x8*)(&Vs[rowd * 64 + ((quad + 4) ^ r7) * 8]);
#pragma unroll
            for (int f = 0; f < 2; ++f) {
                accO[f][nt] = __builtin_amdgcn_mfma_f32_16x16x32_bf16(pf0[f], vf0, accO[f][nt], 0, 0, 0);
                accO[f][nt] = __builtin_amdgcn_mfma_f32_16x16x32_bf16(pf1[f], vf1, accO[f][nt], 0, 0, 0);
            }
        }
        __syncthreads();
    }

    // lsum: reduce over the 4 quads sharing l16 (lane's q = f*16+l16)
#pragma unroll
    for (int f = 0; f < 2; ++f) {
        lsum[f] += __shfl_xor(lsum[f], 16, 64);
        lsum[f] += __shfl_xor(lsum[f], 32, 64);
    }

    // epilogue: accO row q = f*16+quad*4+r; fetch 1/lsum from lane quad*4+r
#pragma unroll
    for (int f = 0; f < 2; ++f)
#pragma unroll
        for (int r = 0; r < 4; ++r) {
            float inv = 1.0f / __shfl(lsum[f], quad * 4 + r, 64);
            int n = qt * 128 + wave * 32 + f * 16 + quad * 4 + r;
#pragma unroll
            for (int nt = 0; nt < 4; ++nt) {
                int col = h * DD + nt * 16 + l16;
                Oqkv[(size_t)(b * NN + n) * rs + 2 * CC + col] = (bf16)(accO[f][nt][r] * inv);
            }
        }
}

// ---------------------------------------------------------------------------
extern "C" void kernel_launch(void* const* d_in, const int* in_sizes, int n_in,
                              void* d_out, int out_size, void* d_ws, size_t ws_size,
                              hipStream_t stream) {
    const float* x     = (const float*)d_in[0];
    const float* cosb  = (const float*)d_in[1];
    const float* sinb  = (const float*)d_in[2];
    const float* qkv_w = (const float*)d_in[3];
    const float* qnw   = (const float*)d_in[4];
    const float* knw   = (const float*)d_in[5];
    const float* pw    = (const float*)d_in[6];
    const float* pb    = (const float*)d_in[7];
    float* out = (float*)d_out;

    bf16* ws  = (bf16*)d_ws;
    bf16* xb  = ws + OFF_X;
    bf16* qwb = ws + OFF_QW;
    bf16* pwb = ws + OFF_PW;
    bf16* qkv = ws + OFF_QKV;
    bf16* vt  = (bf16*)d_out;   // scratch: Vt [B*H][D][N] = 12.6 MB of the
                                // 25.2 MB out buffer; proj overwrites it last.

    const int M = BB * NN;  // 8192

    // 0) cast MFMA operands to bf16 (vectorized 8/thread)
    convert3<<<1024, 256, 0, stream>>>(x, qkv_w, pw, ws);

    // 1) QKV projection + fused RMSNorm/RoPE/CEXP; v-sector written
    //    transposed straight to Vt (transpose_v kernel deleted)
    dim3 g1(3 * CC / 128, M / 128);
    gemm_qkv<<<g1, 256, 0, stream>>>(xb, qwb, qkv, vt, cosb, sinb, qnw, knw);

    // 2) Flash attention -> v-slice of qkv; 128 q-rows, 64-key tiles
    dim3 g4(BB * HH, NN / 128);
    flash_attn<<<g4, 256, 0, stream>>>(qkv, vt, qkv);

    // 3) Output projection (+fp32 bias) -> d_out; 128x64 tiles, 3 blocks/CU
    dim3 g5(CC / 64, M / 128);
    gemm_proj<<<g5, 256, 0, stream>>>(qkv + 2 * CC, pwb, pb, out);
}

// Round 6
// 228.936 us; speedup vs baseline: 1.1935x; 1.0110x over previous
//
#include <hip/hip_runtime.h>
#include <hip/hip_bf16.h>

// Problem constants (B=4, N=2048, C=768, H=12, D=64)
#define BB 4
#define NN 2048
#define CC 768
#define HH 12
#define DD 64

typedef __bf16 bf16;
typedef __attribute__((ext_vector_type(8))) __bf16 bf16x8;
typedef __attribute__((ext_vector_type(4))) __bf16 bf16x4;
typedef __attribute__((ext_vector_type(4))) float f32x4;

// ---- workspace layout (bf16 elems) ----------------------------------------
#define SZ_X    (BB * NN * CC)              // 6291456
#define SZ_QKVW (3 * CC * CC)               // 1769472
#define SZ_PW   (CC * CC)                   // 589824
#define SZ_QKV  ((size_t)BB * NN * 3 * CC)  // 18874368

#define OFF_X    0
#define OFF_QW   (OFF_X + SZ_X)
#define OFF_PW   (OFF_QW + SZ_QKVW)
#define OFF_QKV  (OFF_PW + SZ_PW)           // end = 27525120 elems = 55.1 MB
// Vt [B*H][D][N] (12.6 MB) lives in d_out (25.2 MB f32 scratch until proj).

// Direct-to-LDS 16B DMA; source chunk XOR-swizzled to kill read conflicts.
__device__ __forceinline__ void async16(const bf16* g, bf16* l) {
    __builtin_amdgcn_global_load_lds(
        (const __attribute__((address_space(1))) unsigned int*)g,
        (__attribute__((address_space(3))) unsigned int*)l, 16, 0, 0);
}

// ---------------------------------------------------------------------------
// Vectorized f32 -> bf16 casts: 8 elems/thread (2x f32x4 load, 1x bf16x8 store).
// ---------------------------------------------------------------------------
__device__ __forceinline__ void cast8(const float* __restrict__ src,
                                      bf16* __restrict__ dst, int i) {
    f32x4 a = ((const f32x4*)src)[2 * i];
    f32x4 b = ((const f32x4*)src)[2 * i + 1];
    bf16x8 o;
#pragma unroll
    for (int j = 0; j < 4; ++j) { o[j] = (bf16)a[j]; o[j + 4] = (bf16)b[j]; }
    ((bf16x8*)dst)[i] = o;
}

__global__ __launch_bounds__(256) void convert3(
    const float* __restrict__ x, const float* __restrict__ qkvw,
    const float* __restrict__ pw, bf16* __restrict__ ws) {
    const int t = blockIdx.x * 256 + threadIdx.x;
    const int S = gridDim.x * 256;
    for (int i = t; i < SZ_X / 8;    i += S) cast8(x,    ws + OFF_X,  i);
    for (int i = t; i < SZ_QKVW / 8; i += S) cast8(qkvw, ws + OFF_QW, i);
    for (int i = t; i < SZ_PW / 8;   i += S) cast8(pw,   ws + OFF_PW, i);
}

// ---------------------------------------------------------------------------
// QKV GEMM with fused RMSNorm+RoPE epilogue + direct-transposed V store
// (verified rounds 4-5, unchanged).
// ---------------------------------------------------------------------------
__global__ __launch_bounds__(256) void gemm_qkv(
    const bf16* __restrict__ A, const bf16* __restrict__ W,
    bf16* __restrict__ C, bf16* __restrict__ Vt,
    const float* __restrict__ cosb, const float* __restrict__ sinb,
    const float* __restrict__ qw, const float* __restrict__ kw) {
    __shared__ __align__(16) bf16 As[128 * 64];
    __shared__ __align__(16) bf16 Bs[128 * 64];
    const int tid  = threadIdx.x;
    const int wave = tid >> 6;
    const int lane = tid & 63;
    const int quad = lane >> 4;
    const int l16  = lane & 15;
    const int m0 = blockIdx.y * 128;
    const int n0 = blockIdx.x * 128;
    const int wm = (wave >> 1) * 64;
    const int wn = (wave & 1) * 64;
    const int srow = lane >> 3;
    const int swz  = (lane & 7) ^ srow;
    const int K = CC;
    const int Nn = 3 * CC;

    f32x4 acc[4][4];
#pragma unroll
    for (int i = 0; i < 4; ++i)
#pragma unroll
        for (int j = 0; j < 4; ++j) acc[i][j] = (f32x4){0.f, 0.f, 0.f, 0.f};

    for (int k0 = 0; k0 < K; k0 += 64) {
#pragma unroll
        for (int i = 0; i < 4; ++i) {
            int row = i * 32 + wave * 8 + srow;
            async16(A + (size_t)(m0 + row) * CC + k0 + swz * 8,
                    &As[(i * 32 + wave * 8) * 64]);
            async16(W + (size_t)(n0 + row) * K + k0 + swz * 8,
                    &Bs[(i * 32 + wave * 8) * 64]);
        }
        __syncthreads();
#pragma unroll
        for (int kk = 0; kk < 2; ++kk) {
            const int slot = ((kk * 4 + quad) ^ (l16 & 7)) * 8;
            bf16x8 af[4], bf[4];
#pragma unroll
            for (int mt = 0; mt < 4; ++mt)
                af[mt] = *(const bf16x8*)(&As[(wm + mt * 16 + l16) * 64 + slot]);
#pragma unroll
            for (int nt = 0; nt < 4; ++nt)
                bf[nt] = *(const bf16x8*)(&Bs[(wn + nt * 16 + l16) * 64 + slot]);
#pragma unroll
            for (int mt = 0; mt < 4; ++mt)
#pragma unroll
                for (int nt = 0; nt < 4; ++nt)
                    acc[mt][nt] = __builtin_amdgcn_mfma_f32_16x16x32_bf16(
                        af[mt], bf[nt], acc[mt][nt], 0, 0, 0);
        }
        __syncthreads();
    }

    const int colblk = n0 + wn;          // 64-aligned; one head of q/k/v
    const int sector = colblk / CC;      // 0=q, 1=k, 2=v
    if (sector == 2) {
        // v: transposed store straight to Vt[bh][d][n]; no qkv store.
        const int head = (colblk >> 6) - 24;     // (colblk - 2*CC)/64
        const int btok = m0 + wm;                // first token row of this wave
        const int bh   = (btok >> 11) * HH + head;
        const int nloc = btok & (NN - 1);
#pragma unroll
        for (int nt = 0; nt < 4; ++nt) {
            const int d = nt * 16 + l16;
            bf16* dst = Vt + ((size_t)bh * DD + d) * NN + nloc + quad * 4;
#pragma unroll
            for (int mt = 0; mt < 4; ++mt) {
                bf16x4 pk;
#pragma unroll
                for (int r = 0; r < 4; ++r) pk[r] = (bf16)acc[mt][nt][r];
                *(bf16x4*)(dst + mt * 16) = pk;
            }
        }
    } else {
        const float* wp = (sector == 0) ? qw : kw;
        const float qs = (sector == 0) ? 0.18033688f : 1.0f;  // CEXP fold
        float wv[4];
#pragma unroll
        for (int nt = 0; nt < 4; ++nt) wv[nt] = wp[nt * 16 + l16];
#pragma unroll
        for (int mt = 0; mt < 4; ++mt)
#pragma unroll
            for (int r = 0; r < 4; ++r) {
                const int row = m0 + wm + mt * 16 + quad * 4 + r;
                const int n   = row & (NN - 1);
                float v[4];
#pragma unroll
                for (int nt = 0; nt < 4; ++nt) v[nt] = acc[mt][nt][r];
                float ss = v[0] * v[0] + v[1] * v[1] + v[2] * v[2] + v[3] * v[3];
                ss += __shfl_xor(ss, 1, 64);
                ss += __shfl_xor(ss, 2, 64);
                ss += __shfl_xor(ss, 4, 64);
                ss += __shfl_xor(ss, 8, 64);
                const float rn = rsqrtf(ss * (1.0f / 64.0f) + 1e-6f);
#pragma unroll
                for (int nt = 0; nt < 4; ++nt) v[nt] *= rn * wv[nt];
                // RoPE: d = nt*16+l16; partner d+-32 = reg nt^2; j = d&31
                const float c0 = cosb[n * 32 + l16];
                const float c1 = cosb[n * 32 + 16 + l16];
                const float s0 = sinb[n * 32 + l16];
                const float s1 = sinb[n * 32 + 16 + l16];
                float y[4];
                y[0] = v[0] * c0 - v[2] * s0;
                y[1] = v[1] * c1 - v[3] * s1;
                y[2] = v[2] * c0 + v[0] * s0;
                y[3] = v[3] * c1 + v[1] * s1;
#pragma unroll
                for (int nt = 0; nt < 4; ++nt) {
                    int col = colblk + nt * 16 + l16;
                    C[(size_t)row * Nn + col] = (bf16)(y[nt] * qs);
                }
            }
    }
}

// ---------------------------------------------------------------------------
// Output projection GEMM, 128x64 tiles, grid = 768 = 3 blocks/CU (verified
// round 5, unchanged).
// ---------------------------------------------------------------------------
__global__ __launch_bounds__(256) void gemm_proj(
    const bf16* __restrict__ A, const bf16* __restrict__ W,
    const float* __restrict__ bias, float* __restrict__ C) {
    __shared__ __align__(16) bf16 As[128 * 64];
    __shared__ __align__(16) bf16 Bs[64 * 64];
    const int tid  = threadIdx.x;
    const int wave = tid >> 6;
    const int lane = tid & 63;
    const int quad = lane >> 4;
    const int l16  = lane & 15;
    const int m0 = blockIdx.y * 128;
    const int n0 = blockIdx.x * 64;
    const int wm = (wave >> 1) * 64;
    const int wn = (wave & 1) * 32;
    const int srow = lane >> 3;
    const int swz  = (lane & 7) ^ srow;
    const int lda = 3 * CC;                 // A = v-slice of qkv
    const int K = CC;

    f32x4 acc[4][2];
#pragma unroll
    for (int i = 0; i < 4; ++i)
#pragma unroll
        for (int j = 0; j < 2; ++j) acc[i][j] = (f32x4){0.f, 0.f, 0.f, 0.f};

    for (int k0 = 0; k0 < K; k0 += 64) {
#pragma unroll
        for (int i = 0; i < 4; ++i) {
            int row = i * 32 + wave * 8 + srow;
            async16(A + (size_t)(m0 + row) * lda + k0 + swz * 8,
                    &As[(i * 32 + wave * 8) * 64]);
        }
#pragma unroll
        for (int i = 0; i < 2; ++i) {
            int row = i * 32 + wave * 8 + srow;
            async16(W + (size_t)(n0 + row) * K + k0 + swz * 8,
                    &Bs[(i * 32 + wave * 8) * 64]);
        }
        __syncthreads();
#pragma unroll
        for (int kk = 0; kk < 2; ++kk) {
            const int slot = ((kk * 4 + quad) ^ (l16 & 7)) * 8;
            bf16x8 af[4], bf[2];
#pragma unroll
            for (int mt = 0; mt < 4; ++mt)
                af[mt] = *(const bf16x8*)(&As[(wm + mt * 16 + l16) * 64 + slot]);
#pragma unroll
            for (int nt = 0; nt < 2; ++nt)
                bf[nt] = *(const bf16x8*)(&Bs[(wn + nt * 16 + l16) * 64 + slot]);
#pragma unroll
            for (int mt = 0; mt < 4; ++mt)
#pragma unroll
                for (int nt = 0; nt < 2; ++nt)
                    acc[mt][nt] = __builtin_amdgcn_mfma_f32_16x16x32_bf16(
                        af[mt], bf[nt], acc[mt][nt], 0, 0, 0);
        }
        __syncthreads();
    }
#pragma unroll
    for (int mt = 0; mt < 4; ++mt)
#pragma unroll
        for (int nt = 0; nt < 2; ++nt)
#pragma unroll
            for (int r = 0; r < 4; ++r) {
                int row = m0 + wm + mt * 16 + quad * 4 + r;
                int col = n0 + wn + nt * 16 + l16;
                C[(size_t)row * CC + col] = acc[mt][nt][r] + bias[col];
            }
}

// ---------------------------------------------------------------------------
// Flash attention.  Round-6 change (G1): 512 threads/block — 8 waves x 16
// q-rows (was 4 x 32).  Same 768-block grid, same 128-row q-tile, same LDS
// bytes (34816: Ks 8K + Vs 8K + Ps 8x16x72x2 = 18K), same K/V LDS image and
// swizzle (each wave now issues 1 K-DMA + 1 V-DMA for rows wave*8..+7).
// Per-wave state halves (f-loop removed), waves/CU 12 -> 24 (2 -> ~5/SIMD):
// 2x TLP to hide the QK->exp->Ps->PV dependency chain that rocprof shows as
// nothing-saturated (Mfma 27 / VALU 43 / LDS ~25% / HBM 5%, Occ 26%).
// ---------------------------------------------------------------------------
__global__ __launch_bounds__(512) void flash_attn(
    const bf16* __restrict__ qkv, const bf16* __restrict__ Vt,
    bf16* __restrict__ Oqkv) {
    __shared__ __align__(16) bf16 Ks[64 * 64];       // [key][d] swizzled
    __shared__ __align__(16) bf16 Vs[64 * 64];       // [d][key] swizzled
    __shared__ __align__(16) bf16 Ps[8][16 * 72];    // per-wave [q][key], padded
    const int tid  = threadIdx.x;
    const int wave = tid >> 6;                       // 0..7
    const int lane = tid & 63;
    const int quad = lane >> 4;
    const int l16  = lane & 15;
    const int r7   = l16 & 7;
    const int bh = blockIdx.x;
    const int qt = blockIdx.y;
    const int b = bh / HH, h = bh % HH;
    const size_t rs = 3 * CC;
    const bf16* Qb  = qkv + (size_t)b * NN * rs + h * DD;
    const bf16* Kb  = Qb + CC;
    const bf16* Vtb = Vt + (size_t)bh * DD * NN;

    // Q fragment: 16 q-rows per wave (q = wave*16 + l16)
    bf16x8 qf[2];
    {
        const int qrow = qt * 128 + wave * 16 + l16;
#pragma unroll
        for (int hf = 0; hf < 2; ++hf)
            qf[hf] = *(const bf16x8*)(Qb + (size_t)qrow * rs + hf * 32 + quad * 8);
    }

    f32x4 accO[4];
#pragma unroll
    for (int i = 0; i < 4; ++i) accO[i] = (f32x4){0.f, 0.f, 0.f, 0.f};
    float lsum = 0.f;

    const int srow = lane >> 3;
    const int swz  = (lane & 7) ^ srow;
    const int strow = wave * 8 + srow;               // staging row 0..63

    for (int kt = 0; kt < NN / 64; ++kt) {
        // stage 64 K-rows + 64 V^T d-rows (1 DMA issue each per wave)
        async16(Kb + (size_t)(kt * 64 + strow) * rs + swz * 8,
                &Ks[(wave * 8) * 64]);
        async16(Vtb + (size_t)strow * NN + kt * 64 + swz * 8,
                &Vs[(wave * 8) * 64]);
        __syncthreads();

        // S^T = (Q K^T)^T via swapped operands; scores already exp2-domain
        f32x4 s[4];
#pragma unroll
        for (int nt = 0; nt < 4; ++nt) {
            const int row = nt * 16 + l16;
            bf16x8 kf0 = *(const bf16x8*)(&Ks[row * 64 + (quad ^ r7) * 8]);
            bf16x8 kf1 = *(const bf16x8*)(&Ks[row * 64 + ((quad + 4) ^ r7) * 8]);
            f32x4 z = (f32x4){0.f, 0.f, 0.f, 0.f};
            z = __builtin_amdgcn_mfma_f32_16x16x32_bf16(kf0, qf[0], z, 0, 0, 0);
            s[nt] = __builtin_amdgcn_mfma_f32_16x16x32_bf16(kf1, qf[1], z, 0, 0, 0);
        }

        // p = exp2(s); packed b64 stores (4 consecutive keys per store)
#pragma unroll
        for (int nt = 0; nt < 4; ++nt) {
            bf16x4 pk;
#pragma unroll
            for (int r = 0; r < 4; ++r) {
                float pv = __builtin_amdgcn_exp2f(s[nt][r]);
                lsum += pv;
                pk[r] = (bf16)pv;
            }
            *(bf16x4*)(&Ps[wave][l16 * 72 + nt * 16 + quad * 4]) = pk;
        }
        // Ps wave-private: wave-local DS drain + compiler fence
        __asm__ volatile("s_waitcnt lgkmcnt(0)" ::: "memory");

        bf16x8 pf0 = *(const bf16x8*)(&Ps[wave][l16 * 72 + quad * 8]);
        bf16x8 pf1 = *(const bf16x8*)(&Ps[wave][l16 * 72 + 32 + quad * 8]);
#pragma unroll
        for (int nt = 0; nt < 4; ++nt) {
            const int rowd = nt * 16 + l16;
            bf16x8 vf0 = *(const bf16x8*)(&Vs[rowd * 64 + (quad ^ r7) * 8]);
            bf16x8 vf1 = *(const bf16x8*)(&Vs[rowd * 64 + ((quad + 4) ^ r7) * 8]);
            accO[nt] = __builtin_amdgcn_mfma_f32_16x16x32_bf16(pf0, vf0, accO[nt], 0, 0, 0);
            accO[nt] = __builtin_amdgcn_mfma_f32_16x16x32_bf16(pf1, vf1, accO[nt], 0, 0, 0);
        }
        __syncthreads();
    }

    // lsum: reduce over the 4 quads sharing l16 (lane's q = l16)
    lsum += __shfl_xor(lsum, 16, 64);
    lsum += __shfl_xor(lsum, 32, 64);

    // epilogue: accO row q = quad*4+r; fetch 1/lsum from lane quad*4+r
#pragma unroll
    for (int r = 0; r < 4; ++r) {
        float inv = 1.0f / __shfl(lsum, quad * 4 + r, 64);
        int n = qt * 128 + wave * 16 + quad * 4 + r;
#pragma unroll
        for (int nt = 0; nt < 4; ++nt) {
            int col = h * DD + nt * 16 + l16;
            Oqkv[(size_t)(b * NN + n) * rs + 2 * CC + col] = (bf16)(accO[nt][r] * inv);
        }
    }
}

// ---------------------------------------------------------------------------
extern "C" void kernel_launch(void* const* d_in, const int* in_sizes, int n_in,
                              void* d_out, int out_size, void* d_ws, size_t ws_size,
                              hipStream_t stream) {
    const float* x     = (const float*)d_in[0];
    const float* cosb  = (const float*)d_in[1];
    const float* sinb  = (const float*)d_in[2];
    const float* qkv_w = (const float*)d_in[3];
    const float* qnw   = (const float*)d_in[4];
    const float* knw   = (const float*)d_in[5];
    const float* pw    = (const float*)d_in[6];
    const float* pb    = (const float*)d_in[7];
    float* out = (float*)d_out;

    bf16* ws  = (bf16*)d_ws;
    bf16* xb  = ws + OFF_X;
    bf16* qwb = ws + OFF_QW;
    bf16* pwb = ws + OFF_PW;
    bf16* qkv = ws + OFF_QKV;
    bf16* vt  = (bf16*)d_out;   // scratch: Vt [B*H][D][N] = 12.6 MB of the
                                // 25.2 MB out buffer; proj overwrites it last.

    const int M = BB * NN;  // 8192

    // 0) cast MFMA operands to bf16 (vectorized 8/thread)
    convert3<<<1024, 256, 0, stream>>>(x, qkv_w, pw, ws);

    // 1) QKV projection + fused RMSNorm/RoPE/CEXP; v-sector written
    //    transposed straight to Vt
    dim3 g1(3 * CC / 128, M / 128);
    gemm_qkv<<<g1, 256, 0, stream>>>(xb, qwb, qkv, vt, cosb, sinb, qnw, knw);

    // 2) Flash attention -> v-slice of qkv; 128 q-rows, 64-key tiles,
    //    8 waves x 16 q-rows per block
    dim3 g4(BB * HH, NN / 128);
    flash_attn<<<g4, 512, 0, stream>>>(qkv, vt, qkv);

    // 3) Output projection (+fp32 bias) -> d_out; 128x64 tiles, 3 blocks/CU
    dim3 g5(CC / 64, M / 128);
    gemm_proj<<<g5, 256, 0, stream>>>(qkv + 2 * CC, pwb, pb, out);
}